// Round 3
// baseline (51579.260 us; speedup 1.0000x reference)
//
#include <hip/hip_runtime.h>
#include <cstddef>

using bf16x8 = __attribute__((ext_vector_type(8))) short;
using f32x4  = __attribute__((ext_vector_type(4))) float;

constexpr int Bb = 128;
constexpr int Tt = 256;
constexpr int Hh = 1024;
constexpr int Oo = 64;
constexpr int NBLK = 82;   // 328 waves: phase-A roles 0..195, phase-B roles 196..327

__device__ __forceinline__ float bf2f(short s) {
  unsigned int u = ((unsigned int)(unsigned short)s) << 16;
  float f;
  __builtin_memcpy(&f, &u, 4);
  return f;
}
__device__ __forceinline__ short f2bf(float f) {
  unsigned int u;
  __builtin_memcpy(&u, &f, 4);
  u += 0x7fffu + ((u >> 16) & 1u);  // round-to-nearest-even
  return (short)(u >> 16);
}

// Monotonic grid barrier; 82 blocks, 256 thr, 0 LDS -> all co-resident on 256 CUs.
__device__ __forceinline__ void grid_barrier(unsigned int* bar, unsigned int target) {
  __syncthreads();
  if (threadIdx.x == 0) {
    __hip_atomic_fetch_add(bar, 1u, __ATOMIC_ACQ_REL, __HIP_MEMORY_SCOPE_AGENT);
    while (__hip_atomic_load(bar, __ATOMIC_ACQUIRE, __HIP_MEMORY_SCOPE_AGENT) < target) {
      __builtin_amdgcn_s_sleep(2);
    }
  }
  __syncthreads();
}

// Per-wave GEMM: acc[64 x 32] += A[mb..mb+63][0..1023] * Wslice^T, weights
// persistent in bfr (registers). A read direct from global, 16B/lane row-gather
// (each dwordx4 inst covers 16 x 64B lines, fully used). 4-deep (16-load)
// pipeline to cover post-barrier LLC latency. No LDS anywhere.
__device__ __forceinline__ void wave_gemm(const short* __restrict__ A, int mb,
                                          int lm, int q,
                                          const bf16x8 (&bfr)[32][2],
                                          f32x4 (&acc)[4][2]) {
  const short* Ap = A + (size_t)(mb + lm) * Hh + q * 8;
  bf16x8 af[4][4];
#pragma unroll
  for (int s = 0; s < 4; ++s)
#pragma unroll
    for (int mt = 0; mt < 4; ++mt)
      af[s][mt] = *(const bf16x8*)(Ap + s * 32 + (size_t)mt * 16 * Hh);
#pragma unroll
  for (int k = 0; k < 32; ++k) {
    const int s = k & 3;
    bf16x8 cur[4];
#pragma unroll
    for (int mt = 0; mt < 4; ++mt) cur[mt] = af[s][mt];
    if (k + 4 < 32) {
#pragma unroll
      for (int mt = 0; mt < 4; ++mt)
        af[s][mt] = *(const bf16x8*)(Ap + (k + 4) * 32 + (size_t)mt * 16 * Hh);
    }
#pragma unroll
    for (int mt = 0; mt < 4; ++mt) {
      acc[mt][0] = __builtin_amdgcn_mfma_f32_16x16x32_bf16(cur[mt], bfr[k][0], acc[mt][0], 0, 0, 0);
      acc[mt][1] = __builtin_amdgcn_mfma_f32_16x16x32_bf16(cur[mt], bfr[k][1], acc[mt][1], 0, 0, 0);
    }
  }
}

// C/D layout (verified m89/m91): col = lane&15, row = (lane>>4)*4 + reg
#define TILE_LOOP(...) do {                                                \
    _Pragma("unroll")                                                      \
    for (int mt = 0; mt < 4; ++mt) {                                       \
      _Pragma("unroll")                                                    \
      for (int n = 0; n < 2; ++n) {                                        \
        _Pragma("unroll")                                                  \
        for (int r = 0; r < 4; ++r) {                                      \
          const int row = mb + mt * 16 + q * 4 + r;                        \
          const int col = nb + n * 16 + lm;                                \
          __VA_ARGS__;                                                     \
        } } } } while (0)

struct RP {
  short* h1a; short* h1b; short* h2bf;
  float* h2f; float* uf; float* ug1f; float* acc2f; float* o1f;
  const short* prex;
  const short* whh1; const short* wih2; const short* whh2;
  const short* wg; const short* wo1; const short* wo2;
  const float* b_ih2; const float* b_hh2;
  const float* bg; const float* bo1; const float* bo2;
  float* out;
  unsigned int* bar;
};

// Roles (gw = blockIdx*4 + wave; role uniform per block, boundaries at x4):
//  A-phase: 0-63 h1 | 64-127 acc2=h2@Whh2+b | 128-191 u-gate(h2 part) | 192-195 out(t-1) head2
//  B-phase: 196-259 h2 blend | 260-323 ug1=h1@Wg1 | 324-327 o1 head1
__global__ void __launch_bounds__(256, 1) rnn_kernel(RP p) {
  const int tid = threadIdx.x;
  const int lane = tid & 63;
  const int wv = tid >> 6;
  const int lm = lane & 15;
  const int q = lane >> 4;
  const int gw = blockIdx.x * 4 + wv;

  int role, g;
  if      (gw < 64)  { role = 0; g = gw; }
  else if (gw < 128) { role = 1; g = gw - 64; }
  else if (gw < 192) { role = 2; g = gw - 128; }
  else if (gw < 196) { role = 3; g = gw - 192; }
  else if (gw < 260) { role = 4; g = gw - 196; }
  else if (gw < 324) { role = 5; g = gw - 260; }
  else               { role = 6; g = gw - 324; }
  const int mb = (g & 1) * 64;
  const int nb = (g >> 1) * 32;

  const short* Wp; int bstride;
  switch (role) {
    case 0: Wp = p.whh1;     bstride = Hh;     break;
    case 1: Wp = p.whh2;     bstride = Hh;     break;
    case 2: Wp = p.wg + Hh;  bstride = 2 * Hh; break;  // Wg columns k>=1024 (h2 part)
    case 3: Wp = p.wo2;      bstride = Hh;     break;
    case 4: Wp = p.wih2;     bstride = Hh;     break;
    case 5: Wp = p.wg;       bstride = 2 * Hh; break;  // Wg columns k<1024 (h1 part)
    default: Wp = p.wo1;     bstride = Hh;     break;
  }

  // Persistent weight slice: 32 cols x K=1024 -> 256 VGPRs, loaded ONCE.
  bf16x8 bfr[32][2];
  {
    const short* w0 = Wp + (size_t)(nb + lm) * bstride + q * 8;
    const short* w1 = w0 + (size_t)16 * bstride;
#pragma unroll
    for (int k = 0; k < 32; ++k) {
      bfr[k][0] = *(const bf16x8*)(w0 + k * 32);
      bfr[k][1] = *(const bf16x8*)(w1 + k * 32);
    }
  }
  // Bias per n-tile column (register-resident; immune to L2 invalidations)
  float bias0 = 0.f, bias1 = 0.f;
  {
    const int c0 = nb + lm, c1 = nb + 16 + lm;
    if (role == 1) { bias0 = p.b_ih2[c0] + p.b_hh2[c0]; bias1 = p.b_ih2[c1] + p.b_hh2[c1]; }
    else if (role == 2) { bias0 = p.bg[c0];  bias1 = p.bg[c1]; }
    else if (role == 3) { bias0 = p.bo2[c0]; bias1 = p.bo2[c1]; }
    else if (role == 6) { bias0 = p.bo1[c0]; bias1 = p.bo1[c1]; }
  }

  unsigned int gen = 0;
  for (int t = 0; t < Tt; ++t) {
    const short* h1in  = (t & 1) ? p.h1b : p.h1a;
    short*       h1out = (t & 1) ? p.h1a : p.h1b;
    // ---------------- Phase A ----------------
    if (role == 0) {
      // hoist prex loads (raw shorts; wait deferred to epilogue)
      short exs[4][2][4];
      const short* pr = p.prex + (size_t)t * Bb * Hh;
#pragma unroll
      for (int mt = 0; mt < 4; ++mt)
#pragma unroll
        for (int n = 0; n < 2; ++n)
#pragma unroll
          for (int r = 0; r < 4; ++r)
            exs[mt][n][r] = pr[(size_t)(mb + mt * 16 + q * 4 + r) * Hh + nb + n * 16 + lm];
      f32x4 acc[4][2];
      const f32x4 z4 = {0.f, 0.f, 0.f, 0.f};
#pragma unroll
      for (int mt = 0; mt < 4; ++mt) { acc[mt][0] = z4; acc[mt][1] = z4; }
      wave_gemm(h1in, mb, lm, q, bfr, acc);
      TILE_LOOP({
        h1out[row * Hh + col] = f2bf(tanhf(acc[mt][n][r] + bf2f(exs[mt][n][r])));
      });
    } else if (role == 1) {
      f32x4 acc[4][2];
#pragma unroll
      for (int mt = 0; mt < 4; ++mt) {
        acc[mt][0] = {bias0, bias0, bias0, bias0};
        acc[mt][1] = {bias1, bias1, bias1, bias1};
      }
      wave_gemm(p.h2bf, mb, lm, q, bfr, acc);
      TILE_LOOP({ p.acc2f[row * Hh + col] = acc[mt][n][r]; });
    } else if (role == 2) {
      if (t > 0) {
        float ex[4][2][4];
#pragma unroll
        for (int mt = 0; mt < 4; ++mt)
#pragma unroll
          for (int n = 0; n < 2; ++n)
#pragma unroll
            for (int r = 0; r < 4; ++r)
              ex[mt][n][r] = p.ug1f[(mb + mt * 16 + q * 4 + r) * Hh + nb + n * 16 + lm];
        f32x4 acc[4][2];
#pragma unroll
        for (int mt = 0; mt < 4; ++mt) {
          acc[mt][0] = {bias0, bias0, bias0, bias0};
          acc[mt][1] = {bias1, bias1, bias1, bias1};
        }
        wave_gemm(p.h2bf, mb, lm, q, bfr, acc);
        TILE_LOOP({
          const float s = acc[mt][n][r] + ex[mt][n][r];
          p.uf[row * Hh + col] = 1.0f / (1.0f + expf(-s));
        });
      }
    } else if (role == 3) {
      if (t > 0) {
        float ex[4][2][4];
#pragma unroll
        for (int mt = 0; mt < 4; ++mt)
#pragma unroll
          for (int n = 0; n < 2; ++n)
#pragma unroll
            for (int r = 0; r < 4; ++r)
              ex[mt][n][r] = p.o1f[(mb + mt * 16 + q * 4 + r) * Oo + nb + n * 16 + lm];
        f32x4 acc[4][2];
#pragma unroll
        for (int mt = 0; mt < 4; ++mt) {
          acc[mt][0] = {bias0, bias0, bias0, bias0};
          acc[mt][1] = {bias1, bias1, bias1, bias1};
        }
        wave_gemm(p.h2bf, mb, lm, q, bfr, acc);
        TILE_LOOP({
          p.out[(size_t)row * (Tt * Oo) + (size_t)(t - 1) * Oo + col] =
              ex[mt][n][r] + tanhf(acc[mt][n][r]);
        });
      }
    }
    gen += NBLK;
    grid_barrier(p.bar, gen);
    // ---------------- Phase B ----------------
    if (role == 4) {
      f32x4 acc[4][2];
      const f32x4 z4 = {0.f, 0.f, 0.f, 0.f};
#pragma unroll
      for (int mt = 0; mt < 4; ++mt) { acc[mt][0] = z4; acc[mt][1] = z4; }
      wave_gemm(h1out, mb, lm, q, bfr, acc);
      TILE_LOOP({
        const int idx = row * Hh + col;
        const float a2  = p.acc2f[idx];
        const float u   = p.uf[idx];
        const float h2o = p.h2f[idx];
        const float hn  = tanhf(acc[mt][n][r] + a2);
        const float nv  = fmaf(u, hn - h2o, h2o);
        p.h2f[idx]  = nv;
        p.h2bf[idx] = f2bf(nv);
      });
    } else if (role == 5) {
      f32x4 acc[4][2];
      const f32x4 z4 = {0.f, 0.f, 0.f, 0.f};
#pragma unroll
      for (int mt = 0; mt < 4; ++mt) { acc[mt][0] = z4; acc[mt][1] = z4; }
      wave_gemm(h1out, mb, lm, q, bfr, acc);
      TILE_LOOP({ p.ug1f[row * Hh + col] = acc[mt][n][r]; });
    } else if (role == 6) {
      f32x4 acc[4][2];
#pragma unroll
      for (int mt = 0; mt < 4; ++mt) {
        acc[mt][0] = {bias0, bias0, bias0, bias0};
        acc[mt][1] = {bias1, bias1, bias1, bias1};
      }
      wave_gemm(h1out, mb, lm, q, bfr, acc);
      TILE_LOOP({ p.o1f[row * Oo + col] = tanhf(acc[mt][n][r]); });
    }
    gen += NBLK;
    grid_barrier(p.bar, gen);
  }
  // final output row t = Tt-1 (h2bf/o1f visible via the last barrier)
  if (role == 3) {
    float ex[4][2][4];
#pragma unroll
    for (int mt = 0; mt < 4; ++mt)
#pragma unroll
      for (int n = 0; n < 2; ++n)
#pragma unroll
        for (int r = 0; r < 4; ++r)
          ex[mt][n][r] = p.o1f[(mb + mt * 16 + q * 4 + r) * Oo + nb + n * 16 + lm];
    f32x4 acc[4][2];
#pragma unroll
    for (int mt = 0; mt < 4; ++mt) {
      acc[mt][0] = {bias0, bias0, bias0, bias0};
      acc[mt][1] = {bias1, bias1, bias1, bias1};
    }
    wave_gemm(p.h2bf, mb, lm, q, bfr, acc);
    TILE_LOOP({
      p.out[(size_t)row * (Tt * Oo) + (size_t)(Tt - 1) * Oo + col] =
          ex[mt][n][r] + tanhf(acc[mt][n][r]);
    });
  }
}

// pre_x[t][b][j] = x[b,t,:] @ W_ih1[j,:] + b_ih1[j] + b_hh1[j]  (stored bf16)
__global__ void __launch_bounds__(256) prex_kernel(
    const float* __restrict__ x, const float* __restrict__ wih1,
    const float* __restrict__ b_ih1, const float* __restrict__ b_hh1,
    short* __restrict__ prex) {
  const int tid = threadIdx.x;
  const int lane = tid & 63;
  const int wv = tid >> 6;
  const int lm = lane & 15;
  const int q = lane >> 4;
  const int bm = blockIdx.x >> 4;
  const int bn = blockIdx.x & 15;
  const int rowbase = bm * 64;
  const int col = bn * 64 + wv * 16 + lm;

  const f32x4 z4 = {0.f, 0.f, 0.f, 0.f};
  f32x4 acc[4];
#pragma unroll
  for (int mt = 0; mt < 4; ++mt) acc[mt] = z4;

#pragma unroll
  for (int kc = 0; kc < 2; ++kc) {
    const float* bp = wih1 + col * 64 + kc * 32 + q * 8;
    bf16x8 bf;
#pragma unroll
    for (int j = 0; j < 8; ++j) bf[j] = f2bf(bp[j]);
#pragma unroll
    for (int mt = 0; mt < 4; ++mt) {
      const float* ap = x + (size_t)(rowbase + mt * 16 + lm) * 64 + kc * 32 + q * 8;
      bf16x8 af;
#pragma unroll
      for (int j = 0; j < 8; ++j) af[j] = f2bf(ap[j]);
      acc[mt] = __builtin_amdgcn_mfma_f32_16x16x32_bf16(af, bf, acc[mt], 0, 0, 0);
    }
  }
  const float bia = b_ih1[col] + b_hh1[col];
#pragma unroll
  for (int mt = 0; mt < 4; ++mt) {
#pragma unroll
    for (int r = 0; r < 4; ++r) {
      const int row = rowbase + mt * 16 + q * 4 + r;  // row = b*256 + t
      const int b  = row >> 8;
      const int tt = row & 255;
      prex[((size_t)tt * Bb + b) * Hh + col] = f2bf(acc[mt][r] + bia);
    }
  }
}

__global__ void conv_kernel(const float* __restrict__ s, short* __restrict__ d, int n) {
  int i = blockIdx.x * blockDim.x + threadIdx.x;
  const int stride = gridDim.x * blockDim.x;
  for (; i < n; i += stride) d[i] = f2bf(s[i]);
}

__global__ void init_kernel(short* h1a, short* h1b, short* h2bf, float* h2f,
                            float* uf, unsigned int* bar) {
  const int i = blockIdx.x * blockDim.x + threadIdx.x;  // exactly 128*1024
  h1a[i] = 0; h1b[i] = 0; h2bf[i] = 0; h2f[i] = 0.f; uf[i] = 1.0f;
  if (i == 0) *bar = 0u;
}

extern "C" void kernel_launch(void* const* d_in, const int* in_sizes, int n_in,
                              void* d_out, int out_size, void* d_ws, size_t ws_size,
                              hipStream_t stream) {
  (void)in_sizes; (void)n_in; (void)out_size; (void)ws_size;
  const float* x      = (const float*)d_in[0];
  const float* W_ih1  = (const float*)d_in[1];
  const float* b_ih1  = (const float*)d_in[2];
  const float* W_hh1  = (const float*)d_in[3];
  const float* b_hh1  = (const float*)d_in[4];
  const float* W_ih2  = (const float*)d_in[5];
  const float* b_ih2  = (const float*)d_in[6];
  const float* W_hh2  = (const float*)d_in[7];
  const float* b_hh2  = (const float*)d_in[8];
  const float* Wg     = (const float*)d_in[9];
  const float* bg     = (const float*)d_in[10];
  const float* Wo1    = (const float*)d_in[11];
  const float* bo1    = (const float*)d_in[12];
  const float* Wo2    = (const float*)d_in[13];
  const float* bo2    = (const float*)d_in[14];

  char* ws = (char*)d_ws;
  size_t off = 0;
  auto alloc = [&](size_t bytes) -> void* {
    void* ptr = ws + off;
    off += (bytes + 255) & ~(size_t)255;
    return ptr;
  };
  short* whh1 = (short*)alloc((size_t)Hh * Hh * 2);
  short* wih2 = (short*)alloc((size_t)Hh * Hh * 2);
  short* whh2 = (short*)alloc((size_t)Hh * Hh * 2);
  short* wg   = (short*)alloc((size_t)Hh * 2 * Hh * 2);
  short* wo1  = (short*)alloc((size_t)Oo * Hh * 2);
  short* wo2  = (short*)alloc((size_t)Oo * Hh * 2);
  short* prex = (short*)alloc((size_t)Bb * Tt * Hh * 2);
  short* h1a  = (short*)alloc((size_t)Bb * Hh * 2);
  short* h1b  = (short*)alloc((size_t)Bb * Hh * 2);
  short* h2bf = (short*)alloc((size_t)Bb * Hh * 2);
  float* h2f  = (float*)alloc((size_t)Bb * Hh * 4);
  float* uf   = (float*)alloc((size_t)Bb * Hh * 4);
  float* ug1f = (float*)alloc((size_t)Bb * Hh * 4);
  float* acc2f= (float*)alloc((size_t)Bb * Hh * 4);
  float* o1f  = (float*)alloc((size_t)Bb * Oo * 4);
  unsigned int* bar = (unsigned int*)alloc(256);

  conv_kernel<<<1024, 256, 0, stream>>>(W_hh1, whh1, Hh * Hh);
  conv_kernel<<<1024, 256, 0, stream>>>(W_ih2, wih2, Hh * Hh);
  conv_kernel<<<1024, 256, 0, stream>>>(W_hh2, whh2, Hh * Hh);
  conv_kernel<<<2048, 256, 0, stream>>>(Wg,    wg,   Hh * 2 * Hh);
  conv_kernel<<<256,  256, 0, stream>>>(Wo1,   wo1,  Oo * Hh);
  conv_kernel<<<256,  256, 0, stream>>>(Wo2,   wo2,  Oo * Hh);
  init_kernel<<<512, 256, 0, stream>>>(h1a, h1b, h2bf, h2f, uf, bar);
  prex_kernel<<<8192, 256, 0, stream>>>(x, W_ih1, b_ih1, b_hh1, prex);

  RP p;
  p.h1a = h1a; p.h1b = h1b; p.h2bf = h2bf;
  p.h2f = h2f; p.uf = uf; p.ug1f = ug1f; p.acc2f = acc2f; p.o1f = o1f;
  p.prex = prex;
  p.whh1 = whh1; p.wih2 = wih2; p.whh2 = whh2;
  p.wg = wg; p.wo1 = wo1; p.wo2 = wo2;
  p.b_ih2 = b_ih2; p.b_hh2 = b_hh2;
  p.bg = bg; p.bo1 = bo1; p.bo2 = bo2;
  p.out = (float*)d_out;
  p.bar = bar;

  rnn_kernel<<<NBLK, 256, 0, stream>>>(p);
}

// Round 5
// 16724.513 us; speedup vs baseline: 3.0841x; 3.0841x over previous
//
#include <hip/hip_runtime.h>
#include <cstddef>

using bf16x8 = __attribute__((ext_vector_type(8))) short;
using f32x4  = __attribute__((ext_vector_type(4))) float;

constexpr int Bb = 128;
constexpr int Tt = 256;
constexpr int Hh = 1024;
constexpr int Oo = 64;
constexpr int NBLK = 196;   // 784 waves; wave-level tasks, no intra-block coupling

__device__ __forceinline__ float bf2f(short s) {
  unsigned int u = ((unsigned int)(unsigned short)s) << 16;
  float f;
  __builtin_memcpy(&f, &u, 4);
  return f;
}
__device__ __forceinline__ short f2bf(float f) {
  unsigned int u;
  __builtin_memcpy(&u, &f, 4);
  u += 0x7fffu + ((u >> 16) & 1u);  // round-to-nearest-even
  return (short)(u >> 16);
}
__device__ __forceinline__ bf16x8 as_bf(int4 v) {
  union { int4 i; bf16x8 b; } u; u.i = v; return u.b;
}

// Grid barrier, low-pollution version:
//  - RELEASE fetch_add: waits vmcnt(0) + writes back this XCD's dirty L2 once.
//  - RELAXED spin loads: bypass L2 to the coherence point, NO buffer_inv per
//    poll (the round-2 ACQUIRE spin invalidated L2 continuously, machine-wide).
//  - One ACQUIRE fence per block after wakeup: single L2 invalidate per phase.
__device__ __forceinline__ void grid_barrier(unsigned int* bar, unsigned int target) {
  __syncthreads();
  if (threadIdx.x == 0) {
    __hip_atomic_fetch_add(bar, 1u, __ATOMIC_RELEASE, __HIP_MEMORY_SCOPE_AGENT);
    while (__hip_atomic_load(bar, __ATOMIC_RELAXED, __HIP_MEMORY_SCOPE_AGENT) < target)
      __builtin_amdgcn_s_sleep(2);
  }
  __syncthreads();
  __builtin_amdgcn_fence(__ATOMIC_ACQUIRE, "agent");
}

// Per-wave GEMM, 16x32 output tile, K=1024, no LDS, no __syncthreads.
// Per chunk: 1 A-load + 2 B-loads (16B each) + 2 MFMA. 8-deep register
// pipeline (24 loads in flight); compiler inserts fine-grained vmcnt.
__device__ __forceinline__ void wave_gemm16(
    const short* __restrict__ A, int mb, int lm, int q,
    const short* __restrict__ Bw, int bstride, int nb,
    f32x4 (&acc)[2]) {
  const short* ap  = A  + (size_t)(mb + lm) * Hh + q * 8;
  const short* bp0 = Bw + (size_t)(nb + lm) * bstride + q * 8;
  const short* bp1 = bp0 + (size_t)16 * bstride;
  int4 av[8], b0v[8], b1v[8];
#pragma unroll
  for (int c = 0; c < 8; ++c) {
    av[c]  = *(const int4*)(ap  + c * 32);
    b0v[c] = *(const int4*)(bp0 + c * 32);
    b1v[c] = *(const int4*)(bp1 + c * 32);
  }
#pragma unroll
  for (int c = 0; c < 32; ++c) {
    const int s = c & 7;
    const bf16x8 a  = as_bf(av[s]);
    const bf16x8 b0 = as_bf(b0v[s]);
    const bf16x8 b1 = as_bf(b1v[s]);
    if (c + 8 < 32) {
      av[s]  = *(const int4*)(ap  + (c + 8) * 32);
      b0v[s] = *(const int4*)(bp0 + (c + 8) * 32);
      b1v[s] = *(const int4*)(bp1 + (c + 8) * 32);
    }
    acc[0] = __builtin_amdgcn_mfma_f32_16x16x32_bf16(a, b0, acc[0], 0, 0, 0);
    acc[1] = __builtin_amdgcn_mfma_f32_16x16x32_bf16(a, b1, acc[1], 0, 0, 0);
  }
}

// C/D layout (verified m89/m91): col = lane&15, row = (lane>>4)*4 + reg
#define TL(MB, NB, ...) do {                                               \
    _Pragma("unroll")                                                      \
    for (int n = 0; n < 2; ++n) {                                          \
      _Pragma("unroll")                                                    \
      for (int r = 0; r < 4; ++r) {                                        \
        const int row = (MB) + q * 4 + r;                                  \
        const int col = (NB) + n * 16 + lm;                                \
        const float z = acc[n][r];                                         \
        __VA_ARGS__;                                                       \
      } } } while (0)

#define ZACC() do { const f32x4 z4 = {0.f,0.f,0.f,0.f}; acc[0] = z4; acc[1] = z4; } while (0)

struct RP {
  short* h1a; short* h1b; short* h2bf;
  float* h2f; float* uf; float* ug1f; float* acc2f; float* o1f;
  const short* prex;
  const short* whh1; const short* wih2; const short* whh2;
  const short* wg; const short* wo1; const short* wo2;
  const float* b_ih2; const float* b_hh2;
  const float* bg; const float* bo1; const float* bo2;
  float* out;
  unsigned int* bar;
};

// Wave tasks (gw = blockIdx*4 + wave, 0..783):
//  Phase A: [0,256) h1 | [256,512) acc2 | [512,768) u-gate | [768,784) out(t-1)
//  Phase B: [0,256) h2 blend | [256,512) ug1 | [512,528) o1 head | rest idle
__global__ void __launch_bounds__(256, 1) rnn_kernel(RP p) {
  const int tid = threadIdx.x;
  const int lane = tid & 63;
  const int wv = tid >> 6;
  const int lm = lane & 15;
  const int q = lane >> 4;
  const int gw = blockIdx.x * 4 + wv;

  // ---- phase-A task ----
  int roleA, gA;
  if      (gw < 256) { roleA = 0; gA = gw; }
  else if (gw < 512) { roleA = 1; gA = gw - 256; }
  else if (gw < 768) { roleA = 2; gA = gw - 512; }
  else               { roleA = 3; gA = gw - 768; }
  const int mbA = (roleA == 3) ? (gA >> 1) * 16 : (gA >> 5) * 16;
  const int nbA = (roleA == 3) ? (gA & 1) * 32  : (gA & 31) * 32;
  const short* WA; int bsA;
  switch (roleA) {
    case 0: WA = p.whh1;    bsA = Hh;     break;
    case 1: WA = p.whh2;    bsA = Hh;     break;
    case 2: WA = p.wg + Hh; bsA = 2 * Hh; break;   // Wg, h2 half
    default: WA = p.wo2;    bsA = Hh;     break;
  }
  float bA0 = 0.f, bA1 = 0.f;
  {
    const int c0 = nbA + lm, c1 = nbA + 16 + lm;
    if (roleA == 1) { bA0 = p.b_ih2[c0] + p.b_hh2[c0]; bA1 = p.b_ih2[c1] + p.b_hh2[c1]; }
    else if (roleA == 2) { bA0 = p.bg[c0];  bA1 = p.bg[c1]; }
    else if (roleA == 3) { bA0 = p.bo2[c0]; bA1 = p.bo2[c1]; }
  }

  // ---- phase-B task ----
  int roleB, gB;
  if      (gw < 256) { roleB = 4; gB = gw; }
  else if (gw < 512) { roleB = 5; gB = gw - 256; }
  else if (gw < 528) { roleB = 6; gB = gw - 512; }
  else               { roleB = 7; gB = 0; }       // idle
  const int mbB = (roleB == 6) ? (gB >> 1) * 16 : (gB >> 5) * 16;
  const int nbB = (roleB == 6) ? (gB & 1) * 32  : (gB & 31) * 32;
  const short* WB = p.wo1; int bsB = Hh;
  if (roleB == 4) { WB = p.wih2; bsB = Hh; }
  else if (roleB == 5) { WB = p.wg; bsB = 2 * Hh; }  // Wg, h1 half
  float bB0 = 0.f, bB1 = 0.f;
  if (roleB == 6) { bB0 = p.bo1[nbB + lm]; bB1 = p.bo1[nbB + 16 + lm]; }

  f32x4 acc[2];
  unsigned int gen = 0;
  for (int t = 0; t < Tt; ++t) {
    const short* h1in  = (t & 1) ? p.h1b : p.h1a;
    short*       h1out = (t & 1) ? p.h1a : p.h1b;
    // ---------------- Phase A ----------------
    if (roleA == 0) {
      ZACC();
      wave_gemm16(h1in, mbA, lm, q, WA, bsA, nbA, acc);
      const short* pr = p.prex + (size_t)t * Bb * Hh;
      TL(mbA, nbA, {
        h1out[row * Hh + col] = f2bf(tanhf(z + bf2f(pr[(size_t)row * Hh + col])));
      });
    } else if (roleA == 1) {
      ZACC();
      wave_gemm16(p.h2bf, mbA, lm, q, WA, bsA, nbA, acc);
      TL(mbA, nbA, { p.acc2f[row * Hh + col] = z + (n ? bA1 : bA0); });
    } else if (roleA == 2) {
      if (t > 0) {
        ZACC();
        wave_gemm16(p.h2bf, mbA, lm, q, WA, bsA, nbA, acc);
        TL(mbA, nbA, {
          const float s = z + p.ug1f[row * Hh + col] + (n ? bA1 : bA0);
          p.uf[row * Hh + col] = 1.0f / (1.0f + expf(-s));
        });
      }
    } else {
      if (t > 0) {
        ZACC();
        wave_gemm16(p.h2bf, mbA, lm, q, WA, bsA, nbA, acc);
        TL(mbA, nbA, {
          p.out[(size_t)row * (Tt * Oo) + (size_t)(t - 1) * Oo + col] =
              p.o1f[row * Oo + col] + tanhf(z + (n ? bA1 : bA0));
        });
      }
    }
    gen += NBLK;
    grid_barrier(p.bar, gen);
    // ---------------- Phase B ----------------
    if (roleB == 4) {
      ZACC();
      wave_gemm16(h1out, mbB, lm, q, WB, bsB, nbB, acc);
      TL(mbB, nbB, {
        const int idx = row * Hh + col;
        const float hn  = tanhf(z + p.acc2f[idx]);
        const float u   = p.uf[idx];
        const float h2o = p.h2f[idx];
        const float nv  = fmaf(u, hn - h2o, h2o);
        p.h2f[idx]  = nv;
        p.h2bf[idx] = f2bf(nv);
      });
    } else if (roleB == 5) {
      ZACC();
      wave_gemm16(h1out, mbB, lm, q, WB, bsB, nbB, acc);
      TL(mbB, nbB, { p.ug1f[row * Hh + col] = z; });
    } else if (roleB == 6) {
      ZACC();
      wave_gemm16(h1out, mbB, lm, q, WB, bsB, nbB, acc);
      TL(mbB, nbB, { p.o1f[row * Oo + col] = tanhf(z + (n ? bB1 : bB0)); });
    }
    gen += NBLK;
    grid_barrier(p.bar, gen);
  }
  // tail: out rows for t = Tt-1 (state visible via last barrier's acquire)
  if (roleA == 3) {
    ZACC();
    wave_gemm16(p.h2bf, mbA, lm, q, WA, bsA, nbA, acc);
    TL(mbA, nbA, {
      p.out[(size_t)row * (Tt * Oo) + (size_t)(Tt - 1) * Oo + col] =
          p.o1f[row * Oo + col] + tanhf(z + (n ? bA1 : bA0));
    });
  }
}

// pre_x[t][b][j] = x[b,t,:] @ W_ih1[j,:] + b_ih1[j] + b_hh1[j]  (stored bf16)
__global__ void __launch_bounds__(256) prex_kernel(
    const float* __restrict__ x, const float* __restrict__ wih1,
    const float* __restrict__ b_ih1, const float* __restrict__ b_hh1,
    short* __restrict__ prex) {
  const int tid = threadIdx.x;
  const int lane = tid & 63;
  const int wv = tid >> 6;
  const int lm = lane & 15;
  const int q = lane >> 4;
  const int bm = blockIdx.x >> 4;
  const int bn = blockIdx.x & 15;
  const int rowbase = bm * 64;
  const int col = bn * 64 + wv * 16 + lm;

  const f32x4 z4 = {0.f, 0.f, 0.f, 0.f};
  f32x4 acc[4];
#pragma unroll
  for (int mt = 0; mt < 4; ++mt) acc[mt] = z4;

#pragma unroll
  for (int kc = 0; kc < 2; ++kc) {
    const float* bp = wih1 + col * 64 + kc * 32 + q * 8;
    bf16x8 bf;
#pragma unroll
    for (int j = 0; j < 8; ++j) bf[j] = f2bf(bp[j]);
#pragma unroll
    for (int mt = 0; mt < 4; ++mt) {
      const float* ap = x + (size_t)(rowbase + mt * 16 + lm) * 64 + kc * 32 + q * 8;
      bf16x8 af;
#pragma unroll
      for (int j = 0; j < 8; ++j) af[j] = f2bf(ap[j]);
      acc[mt] = __builtin_amdgcn_mfma_f32_16x16x32_bf16(af, bf, acc[mt], 0, 0, 0);
    }
  }
  const float bia = b_ih1[col] + b_hh1[col];
#pragma unroll
  for (int mt = 0; mt < 4; ++mt) {
#pragma unroll
    for (int r = 0; r < 4; ++r) {
      const int row = rowbase + mt * 16 + q * 4 + r;  // row = b*256 + t
      const int b  = row >> 8;
      const int tt = row & 255;
      prex[((size_t)tt * Bb + b) * Hh + col] = f2bf(acc[mt][r] + bia);
    }
  }
}

__global__ void conv_kernel(const float* __restrict__ s, short* __restrict__ d, int n) {
  int i = blockIdx.x * blockDim.x + threadIdx.x;
  const int stride = gridDim.x * blockDim.x;
  for (; i < n; i += stride) d[i] = f2bf(s[i]);
}

__global__ void init_kernel(short* h1a, short* h1b, short* h2bf, float* h2f,
                            float* uf, unsigned int* bar) {
  const int i = blockIdx.x * blockDim.x + threadIdx.x;  // exactly 128*1024
  h1a[i] = 0; h1b[i] = 0; h2bf[i] = 0; h2f[i] = 0.f; uf[i] = 1.0f;
  if (i == 0) *bar = 0u;
}

extern "C" void kernel_launch(void* const* d_in, const int* in_sizes, int n_in,
                              void* d_out, int out_size, void* d_ws, size_t ws_size,
                              hipStream_t stream) {
  (void)in_sizes; (void)n_in; (void)out_size; (void)ws_size;
  const float* x      = (const float*)d_in[0];
  const float* W_ih1  = (const float*)d_in[1];
  const float* b_ih1  = (const float*)d_in[2];
  const float* W_hh1  = (const float*)d_in[3];
  const float* b_hh1  = (const float*)d_in[4];
  const float* W_ih2  = (const float*)d_in[5];
  const float* b_ih2  = (const float*)d_in[6];
  const float* W_hh2  = (const float*)d_in[7];
  const float* b_hh2  = (const float*)d_in[8];
  const float* Wg     = (const float*)d_in[9];
  const float* bg     = (const float*)d_in[10];
  const float* Wo1    = (const float*)d_in[11];
  const float* bo1    = (const float*)d_in[12];
  const float* Wo2    = (const float*)d_in[13];
  const float* bo2    = (const float*)d_in[14];

  char* ws = (char*)d_ws;
  size_t off = 0;
  auto alloc = [&](size_t bytes) -> void* {
    void* ptr = ws + off;
    off += (bytes + 255) & ~(size_t)255;
    return ptr;
  };
  short* whh1 = (short*)alloc((size_t)Hh * Hh * 2);
  short* wih2 = (short*)alloc((size_t)Hh * Hh * 2);
  short* whh2 = (short*)alloc((size_t)Hh * Hh * 2);
  short* wg   = (short*)alloc((size_t)Hh * 2 * Hh * 2);
  short* wo1  = (short*)alloc((size_t)Oo * Hh * 2);
  short* wo2  = (short*)alloc((size_t)Oo * Hh * 2);
  short* prex = (short*)alloc((size_t)Bb * Tt * Hh * 2);
  short* h1a  = (short*)alloc((size_t)Bb * Hh * 2);
  short* h1b  = (short*)alloc((size_t)Bb * Hh * 2);
  short* h2bf = (short*)alloc((size_t)Bb * Hh * 2);
  float* h2f  = (float*)alloc((size_t)Bb * Hh * 4);
  float* uf   = (float*)alloc((size_t)Bb * Hh * 4);
  float* ug1f = (float*)alloc((size_t)Bb * Hh * 4);
  float* acc2f= (float*)alloc((size_t)Bb * Hh * 4);
  float* o1f  = (float*)alloc((size_t)Bb * Oo * 4);
  unsigned int* bar = (unsigned int*)alloc(256);

  conv_kernel<<<1024, 256, 0, stream>>>(W_hh1, whh1, Hh * Hh);
  conv_kernel<<<1024, 256, 0, stream>>>(W_ih2, wih2, Hh * Hh);
  conv_kernel<<<1024, 256, 0, stream>>>(W_hh2, whh2, Hh * Hh);
  conv_kernel<<<2048, 256, 0, stream>>>(Wg,    wg,   Hh * 2 * Hh);
  conv_kernel<<<256,  256, 0, stream>>>(Wo1,   wo1,  Oo * Hh);
  conv_kernel<<<256,  256, 0, stream>>>(Wo2,   wo2,  Oo * Hh);
  init_kernel<<<512, 256, 0, stream>>>(h1a, h1b, h2bf, h2f, uf, bar);
  prex_kernel<<<8192, 256, 0, stream>>>(x, W_ih1, b_ih1, b_hh1, prex);

  RP p;
  p.h1a = h1a; p.h1b = h1b; p.h2bf = h2bf;
  p.h2f = h2f; p.uf = uf; p.ug1f = ug1f; p.acc2f = acc2f; p.o1f = o1f;
  p.prex = prex;
  p.whh1 = whh1; p.wih2 = wih2; p.whh2 = whh2;
  p.wg = wg; p.wo1 = wo1; p.wo2 = wo2;
  p.b_ih2 = b_ih2; p.b_hh2 = b_hh2;
  p.bg = bg; p.bo1 = bo1; p.bo2 = bo2;
  p.out = (float*)d_out;
  p.bar = bar;

  rnn_kernel<<<NBLK, 256, 0, stream>>>(p);
}

// Round 6
// 16533.949 us; speedup vs baseline: 3.1196x; 1.0115x over previous
//
#include <hip/hip_runtime.h>
#include <cstddef>

using bf16x8 = __attribute__((ext_vector_type(8))) short;
using f32x4  = __attribute__((ext_vector_type(4))) float;

constexpr int Bb = 128;
constexpr int Tt = 256;
constexpr int Hh = 1024;
constexpr int Oo = 64;
constexpr int NBLK = 196;

__device__ __forceinline__ float bf2f(short s) {
  unsigned int u = ((unsigned int)(unsigned short)s) << 16;
  float f;
  __builtin_memcpy(&f, &u, 4);
  return f;
}
__device__ __forceinline__ short f2bf(float f) {
  unsigned int u;
  __builtin_memcpy(&u, &f, 4);
  u += 0x7fffu + ((u >> 16) & 1u);  // round-to-nearest-even
  return (short)(u >> 16);
}
__device__ __forceinline__ bf16x8 as_bf(int4 v) {
  union { int4 i; bf16x8 b; } u; u.i = v; return u.b;
}

// Agent-scope relaxed (sc1: bypass per-XCD L2, coherent at LLC) state access.
__device__ __forceinline__ float ldf(const float* p) {
  return __hip_atomic_load((float*)p, __ATOMIC_RELAXED, __HIP_MEMORY_SCOPE_AGENT);
}
__device__ __forceinline__ void stf(float* p, float v) {
  __hip_atomic_store(p, v, __ATOMIC_RELAXED, __HIP_MEMORY_SCOPE_AGENT);
}
// 16B of bf16 state as 4 coherent dword loads
__device__ __forceinline__ int4 ld_sc16(const short* p) {
  unsigned* w = (unsigned*)p;
  int4 v;
  v.x = (int)__hip_atomic_load(w + 0, __ATOMIC_RELAXED, __HIP_MEMORY_SCOPE_AGENT);
  v.y = (int)__hip_atomic_load(w + 1, __ATOMIC_RELAXED, __HIP_MEMORY_SCOPE_AGENT);
  v.z = (int)__hip_atomic_load(w + 2, __ATOMIC_RELAXED, __HIP_MEMORY_SCOPE_AGENT);
  v.w = (int)__hip_atomic_load(w + 3, __ATOMIC_RELAXED, __HIP_MEMORY_SCOPE_AGENT);
  return v;
}

// Grid barrier without any L2 invalidate:
//  - RELEASE fetch_add: vmcnt drain + L2 writeback (clean weights stay valid).
//  - RELAXED spin, s_sleep(32) ~0.85us poll: kills the round-5 one-line
//    contention storm (196 pollers @53ns serialized at one LLC bank).
//  - NO acquire fence: cross-wave state uses sc1 loads that bypass L2.
__device__ __forceinline__ void grid_barrier(unsigned int* bar, unsigned int target) {
  __syncthreads();
  if (threadIdx.x == 0) {
    __hip_atomic_fetch_add(bar, 1u, __ATOMIC_RELEASE, __HIP_MEMORY_SCOPE_AGENT);
    while (__hip_atomic_load(bar, __ATOMIC_RELAXED, __HIP_MEMORY_SCOPE_AGENT) < target)
      __builtin_amdgcn_s_sleep(32);
  }
  __syncthreads();
  asm volatile("" ::: "memory");
}

// Per-wave GEMM, 16x32 output tile, K=1024, no LDS/no __syncthreads.
// A (state): coherent dword loads from LLC. B (weights): plain cached loads,
// permanently L2-hot (never invalidated). 8-deep register pipeline.
__device__ __forceinline__ void wave_gemm16(
    const short* __restrict__ A, int mb, int lm, int q,
    const short* __restrict__ Bw, int bstride, int nb,
    f32x4 (&acc)[2]) {
  const short* ap  = A  + (size_t)(mb + lm) * Hh + q * 8;
  const short* bp0 = Bw + (size_t)(nb + lm) * bstride + q * 8;
  const short* bp1 = bp0 + (size_t)16 * bstride;
  int4 av[8], b0v[8], b1v[8];
#pragma unroll
  for (int c = 0; c < 8; ++c) {
    av[c]  = ld_sc16(ap + c * 32);
    b0v[c] = *(const int4*)(bp0 + c * 32);
    b1v[c] = *(const int4*)(bp1 + c * 32);
  }
#pragma unroll
  for (int c = 0; c < 32; ++c) {
    const int s = c & 7;
    const bf16x8 a  = as_bf(av[s]);
    const bf16x8 b0 = as_bf(b0v[s]);
    const bf16x8 b1 = as_bf(b1v[s]);
    if (c + 8 < 32) {
      av[s]  = ld_sc16(ap + (c + 8) * 32);
      b0v[s] = *(const int4*)(bp0 + (c + 8) * 32);
      b1v[s] = *(const int4*)(bp1 + (c + 8) * 32);
    }
    acc[0] = __builtin_amdgcn_mfma_f32_16x16x32_bf16(a, b0, acc[0], 0, 0, 0);
    acc[1] = __builtin_amdgcn_mfma_f32_16x16x32_bf16(a, b1, acc[1], 0, 0, 0);
  }
}

// C/D layout (verified m89/m91): col = lane&15, row = (lane>>4)*4 + reg
#define TL(MB, NB, ...) do {                                               \
    _Pragma("unroll")                                                      \
    for (int n = 0; n < 2; ++n) {                                          \
      _Pragma("unroll")                                                    \
      for (int r = 0; r < 4; ++r) {                                        \
        const int row = (MB) + q * 4 + r;                                  \
        const int col = (NB) + n * 16 + lm;                                \
        const float z = acc[n][r];                                         \
        __VA_ARGS__;                                                       \
      } } } while (0)

// pack bf16 pair across lane (lm, lm^1) and store one coherent dword from even lm
#define ST_BF16_PAIR(BASE, ROW, COL, HV) do {                              \
    const int _ov = __shfl_xor((int)(unsigned short)(HV), 1, 64);          \
    if ((lm & 1) == 0) {                                                   \
      const unsigned _pk = (unsigned)(unsigned short)(HV) | ((unsigned)_ov << 16); \
      __hip_atomic_store((unsigned*)((BASE) + (ROW) * Hh + (COL)), _pk,    \
                         __ATOMIC_RELAXED, __HIP_MEMORY_SCOPE_AGENT);      \
    } } while (0)

#define ZACC() do { const f32x4 z4 = {0.f,0.f,0.f,0.f}; acc[0] = z4; acc[1] = z4; } while (0)

struct RP {
  short* h1a; short* h1b; short* h2bf;
  float* h2f; float* uf; float* ug1f; float* acc2f; float* o1f;
  const short* prex;
  const short* whh1; const short* wih2; const short* whh2;
  const short* wg; const short* wo1; const short* wo2;
  const float* b_ih2; const float* b_hh2;
  const float* bg; const float* bo1; const float* bo2;
  float* out;
  unsigned int* bar;
};

// Wave tasks (gw = blockIdx*4 + wave, 0..783):
//  Phase A: [0,256) h1 | [256,512) acc2 | [512,768) u-gate | [768,784) out(t-1)
//  Phase B: [0,256) h2 blend | [256,512) ug1 | [512,528) o1 head | rest idle
__global__ void __launch_bounds__(256, 1) rnn_kernel(RP p) {
  const int tid = threadIdx.x;
  const int lane = tid & 63;
  const int wv = tid >> 6;
  const int lm = lane & 15;
  const int q = lane >> 4;
  const int gw = blockIdx.x * 4 + wv;

  int roleA, gA;
  if      (gw < 256) { roleA = 0; gA = gw; }
  else if (gw < 512) { roleA = 1; gA = gw - 256; }
  else if (gw < 768) { roleA = 2; gA = gw - 512; }
  else               { roleA = 3; gA = gw - 768; }
  const int mbA = (roleA == 3) ? (gA >> 1) * 16 : (gA >> 5) * 16;
  const int nbA = (roleA == 3) ? (gA & 1) * 32  : (gA & 31) * 32;
  const short* WA; int bsA;
  switch (roleA) {
    case 0: WA = p.whh1;    bsA = Hh;     break;
    case 1: WA = p.whh2;    bsA = Hh;     break;
    case 2: WA = p.wg + Hh; bsA = 2 * Hh; break;   // Wg, h2 half
    default: WA = p.wo2;    bsA = Hh;     break;
  }
  float bA0 = 0.f, bA1 = 0.f;
  {
    const int c0 = nbA + lm, c1 = nbA + 16 + lm;
    if (roleA == 1) { bA0 = p.b_ih2[c0] + p.b_hh2[c0]; bA1 = p.b_ih2[c1] + p.b_hh2[c1]; }
    else if (roleA == 2) { bA0 = p.bg[c0];  bA1 = p.bg[c1]; }
    else if (roleA == 3) { bA0 = p.bo2[c0]; bA1 = p.bo2[c1]; }
  }

  int roleB, gB;
  if      (gw < 256) { roleB = 4; gB = gw; }
  else if (gw < 512) { roleB = 5; gB = gw - 256; }
  else if (gw < 528) { roleB = 6; gB = gw - 512; }
  else               { roleB = 7; gB = 0; }       // idle
  const int mbB = (roleB == 6) ? (gB >> 1) * 16 : (gB >> 5) * 16;
  const int nbB = (roleB == 6) ? (gB & 1) * 32  : (gB & 31) * 32;
  const short* WB = p.wo1; int bsB = Hh;
  if (roleB == 4) { WB = p.wih2; bsB = Hh; }
  else if (roleB == 5) { WB = p.wg; bsB = 2 * Hh; }  // Wg, h1 half
  float bB0 = 0.f, bB1 = 0.f;
  if (roleB == 6) { bB0 = p.bo1[nbB + lm]; bB1 = p.bo1[nbB + 16 + lm]; }

  f32x4 acc[2];
  unsigned int gen = 0;
  for (int t = 0; t < Tt; ++t) {
    const short* h1in  = (t & 1) ? p.h1b : p.h1a;
    short*       h1out = (t & 1) ? p.h1a : p.h1b;
    // ---------------- Phase A ----------------
    if (roleA == 0) {
      // prefetch prex (plain cached; streamed once) before the GEMM
      short prs[2][4];
      const short* pr = p.prex + (size_t)t * Bb * Hh;
#pragma unroll
      for (int n = 0; n < 2; ++n)
#pragma unroll
        for (int r = 0; r < 4; ++r)
          prs[n][r] = pr[(size_t)(mbA + q * 4 + r) * Hh + nbA + n * 16 + lm];
      ZACC();
      wave_gemm16(h1in, mbA, lm, q, WA, bsA, nbA, acc);
      TL(mbA, nbA, {
        const short hv = f2bf(tanhf(z + bf2f(prs[n][r])));
        ST_BF16_PAIR(h1out, row, col, hv);
      });
    } else if (roleA == 1) {
      ZACC();
      wave_gemm16(p.h2bf, mbA, lm, q, WA, bsA, nbA, acc);
      TL(mbA, nbA, { stf(p.acc2f + row * Hh + col, z + (n ? bA1 : bA0)); });
    } else if (roleA == 2) {
      if (t > 0) {
        float ex[2][4];
#pragma unroll
        for (int n = 0; n < 2; ++n)
#pragma unroll
          for (int r = 0; r < 4; ++r)
            ex[n][r] = ldf(p.ug1f + (mbA + q * 4 + r) * Hh + nbA + n * 16 + lm);
        ZACC();
        wave_gemm16(p.h2bf, mbA, lm, q, WA, bsA, nbA, acc);
        TL(mbA, nbA, {
          const float s = z + ex[n][r] + (n ? bA1 : bA0);
          stf(p.uf + row * Hh + col, 1.0f / (1.0f + expf(-s)));
        });
      }
    } else {
      if (t > 0) {
        float ex[2][4];
#pragma unroll
        for (int n = 0; n < 2; ++n)
#pragma unroll
          for (int r = 0; r < 4; ++r)
            ex[n][r] = ldf(p.o1f + (mbA + q * 4 + r) * Oo + nbA + n * 16 + lm);
        ZACC();
        wave_gemm16(p.h2bf, mbA, lm, q, WA, bsA, nbA, acc);
        TL(mbA, nbA, {
          p.out[(size_t)row * (Tt * Oo) + (size_t)(t - 1) * Oo + col] =
              ex[n][r] + tanhf(z + (n ? bA1 : bA0));
        });
      }
    }
    gen += NBLK;
    grid_barrier(p.bar, gen);
    // ---------------- Phase B ----------------
    if (roleB == 4) {
      float a2[2][4], uu[2][4], h2o[2][4];
#pragma unroll
      for (int n = 0; n < 2; ++n)
#pragma unroll
        for (int r = 0; r < 4; ++r) {
          const int idx = (mbB + q * 4 + r) * Hh + nbB + n * 16 + lm;
          a2[n][r]  = ldf(p.acc2f + idx);
          uu[n][r]  = ldf(p.uf + idx);
          h2o[n][r] = p.h2f[idx];        // XCD-local (same wave wrote it)
        }
      ZACC();
      wave_gemm16(h1out, mbB, lm, q, WB, bsB, nbB, acc);
      TL(mbB, nbB, {
        const int idx = row * Hh + col;
        const float hn = tanhf(z + a2[n][r]);
        const float nv = fmaf(uu[n][r], hn - h2o[n][r], h2o[n][r]);
        p.h2f[idx] = nv;
        const short hv = f2bf(nv);
        ST_BF16_PAIR(p.h2bf, row, col, hv);
      });
    } else if (roleB == 5) {
      ZACC();
      wave_gemm16(h1out, mbB, lm, q, WB, bsB, nbB, acc);
      TL(mbB, nbB, { stf(p.ug1f + row * Hh + col, z); });
    } else if (roleB == 6) {
      ZACC();
      wave_gemm16(h1out, mbB, lm, q, WB, bsB, nbB, acc);
      TL(mbB, nbB, { stf(p.o1f + row * Oo + col, tanhf(z + (n ? bB1 : bB0))); });
    }
    gen += NBLK;
    grid_barrier(p.bar, gen);
  }
  // tail: out rows for t = Tt-1 (state visible via coherent loads)
  if (roleA == 3) {
    float ex[2][4];
#pragma unroll
    for (int n = 0; n < 2; ++n)
#pragma unroll
      for (int r = 0; r < 4; ++r)
        ex[n][r] = ldf(p.o1f + (mbA + q * 4 + r) * Oo + nbA + n * 16 + lm);
    ZACC();
    wave_gemm16(p.h2bf, mbA, lm, q, WA, bsA, nbA, acc);
    TL(mbA, nbA, {
      p.out[(size_t)row * (Tt * Oo) + (size_t)(Tt - 1) * Oo + col] =
          ex[n][r] + tanhf(z + (n ? bA1 : bA0));
    });
  }
}

// pre_x[t][b][j] = x[b,t,:] @ W_ih1[j,:] + b_ih1[j] + b_hh1[j]  (stored bf16)
__global__ void __launch_bounds__(256) prex_kernel(
    const float* __restrict__ x, const float* __restrict__ wih1,
    const float* __restrict__ b_ih1, const float* __restrict__ b_hh1,
    short* __restrict__ prex) {
  const int tid = threadIdx.x;
  const int lane = tid & 63;
  const int wv = tid >> 6;
  const int lm = lane & 15;
  const int q = lane >> 4;
  const int bm = blockIdx.x >> 4;
  const int bn = blockIdx.x & 15;
  const int rowbase = bm * 64;
  const int col = bn * 64 + wv * 16 + lm;

  const f32x4 z4 = {0.f, 0.f, 0.f, 0.f};
  f32x4 acc[4];
#pragma unroll
  for (int mt = 0; mt < 4; ++mt) acc[mt] = z4;

#pragma unroll
  for (int kc = 0; kc < 2; ++kc) {
    const float* bp = wih1 + col * 64 + kc * 32 + q * 8;
    bf16x8 bf;
#pragma unroll
    for (int j = 0; j < 8; ++j) bf[j] = f2bf(bp[j]);
#pragma unroll
    for (int mt = 0; mt < 4; ++mt) {
      const float* ap = x + (size_t)(rowbase + mt * 16 + lm) * 64 + kc * 32 + q * 8;
      bf16x8 af;
#pragma unroll
      for (int j = 0; j < 8; ++j) af[j] = f2bf(ap[j]);
      acc[mt] = __builtin_amdgcn_mfma_f32_16x16x32_bf16(af, bf, acc[mt], 0, 0, 0);
    }
  }
  const float bia = b_ih1[col] + b_hh1[col];
#pragma unroll
  for (int mt = 0; mt < 4; ++mt) {
#pragma unroll
    for (int r = 0; r < 4; ++r) {
      const int row = rowbase + mt * 16 + q * 4 + r;  // row = b*256 + t
      const int b  = row >> 8;
      const int tt = row & 255;
      prex[((size_t)tt * Bb + b) * Hh + col] = f2bf(acc[mt][r] + bia);
    }
  }
}

__global__ void conv_kernel(const float* __restrict__ s, short* __restrict__ d, int n) {
  int i = blockIdx.x * blockDim.x + threadIdx.x;
  const int stride = gridDim.x * blockDim.x;
  for (; i < n; i += stride) d[i] = f2bf(s[i]);
}

__global__ void init_kernel(short* h1a, short* h1b, short* h2bf, float* h2f,
                            float* uf, unsigned int* bar) {
  const int i = blockIdx.x * blockDim.x + threadIdx.x;  // exactly 128*1024
  h1a[i] = 0; h1b[i] = 0; h2bf[i] = 0; h2f[i] = 0.f; uf[i] = 1.0f;
  if (i == 0) *bar = 0u;
}

extern "C" void kernel_launch(void* const* d_in, const int* in_sizes, int n_in,
                              void* d_out, int out_size, void* d_ws, size_t ws_size,
                              hipStream_t stream) {
  (void)in_sizes; (void)n_in; (void)out_size; (void)ws_size;
  const float* x      = (const float*)d_in[0];
  const float* W_ih1  = (const float*)d_in[1];
  const float* b_ih1  = (const float*)d_in[2];
  const float* W_hh1  = (const float*)d_in[3];
  const float* b_hh1  = (const float*)d_in[4];
  const float* W_ih2  = (const float*)d_in[5];
  const float* b_ih2  = (const float*)d_in[6];
  const float* W_hh2  = (const float*)d_in[7];
  const float* b_hh2  = (const float*)d_in[8];
  const float* Wg     = (const float*)d_in[9];
  const float* bg     = (const float*)d_in[10];
  const float* Wo1    = (const float*)d_in[11];
  const float* bo1    = (const float*)d_in[12];
  const float* Wo2    = (const float*)d_in[13];
  const float* bo2    = (const float*)d_in[14];

  char* ws = (char*)d_ws;
  size_t off = 0;
  auto alloc = [&](size_t bytes) -> void* {
    void* ptr = ws + off;
    off += (bytes + 255) & ~(size_t)255;
    return ptr;
  };
  short* whh1 = (short*)alloc((size_t)Hh * Hh * 2);
  short* wih2 = (short*)alloc((size_t)Hh * Hh * 2);
  short* whh2 = (short*)alloc((size_t)Hh * Hh * 2);
  short* wg   = (short*)alloc((size_t)Hh * 2 * Hh * 2);
  short* wo1  = (short*)alloc((size_t)Oo * Hh * 2);
  short* wo2  = (short*)alloc((size_t)Oo * Hh * 2);
  short* prex = (short*)alloc((size_t)Bb * Tt * Hh * 2);
  short* h1a  = (short*)alloc((size_t)Bb * Hh * 2);
  short* h1b  = (short*)alloc((size_t)Bb * Hh * 2);
  short* h2bf = (short*)alloc((size_t)Bb * Hh * 2);
  float* h2f  = (float*)alloc((size_t)Bb * Hh * 4);
  float* uf   = (float*)alloc((size_t)Bb * Hh * 4);
  float* ug1f = (float*)alloc((size_t)Bb * Hh * 4);
  float* acc2f= (float*)alloc((size_t)Bb * Hh * 4);
  float* o1f  = (float*)alloc((size_t)Bb * Oo * 4);
  unsigned int* bar = (unsigned int*)alloc(256);

  conv_kernel<<<1024, 256, 0, stream>>>(W_hh1, whh1, Hh * Hh);
  conv_kernel<<<1024, 256, 0, stream>>>(W_ih2, wih2, Hh * Hh);
  conv_kernel<<<1024, 256, 0, stream>>>(W_hh2, whh2, Hh * Hh);
  conv_kernel<<<2048, 256, 0, stream>>>(Wg,    wg,   Hh * 2 * Hh);
  conv_kernel<<<256,  256, 0, stream>>>(Wo1,   wo1,  Oo * Hh);
  conv_kernel<<<256,  256, 0, stream>>>(Wo2,   wo2,  Oo * Hh);
  init_kernel<<<512, 256, 0, stream>>>(h1a, h1b, h2bf, h2f, uf, bar);
  prex_kernel<<<8192, 256, 0, stream>>>(x, W_ih1, b_ih1, b_hh1, prex);

  RP p;
  p.h1a = h1a; p.h1b = h1b; p.h2bf = h2bf;
  p.h2f = h2f; p.uf = uf; p.ug1f = ug1f; p.acc2f = acc2f; p.o1f = o1f;
  p.prex = prex;
  p.whh1 = whh1; p.wih2 = wih2; p.whh2 = whh2;
  p.wg = wg; p.wo1 = wo1; p.wo2 = wo2;
  p.b_ih2 = b_ih2; p.b_hh2 = b_hh2;
  p.bg = bg; p.bo1 = bo1; p.bo2 = bo2;
  p.out = (float*)d_out;
  p.bar = bar;

  rnn_kernel<<<NBLK, 256, 0, stream>>>(p);
}

// Round 7
// 14339.294 us; speedup vs baseline: 3.5971x; 1.1531x over previous
//
#include <hip/hip_runtime.h>
#include <cstddef>

using bf16x8 = __attribute__((ext_vector_type(8))) short;
using f32x4  = __attribute__((ext_vector_type(4))) float;

constexpr int Bb = 128;
constexpr int Tt = 256;
constexpr int Hh = 1024;
constexpr int Oo = 64;
constexpr int NBLK = 196;

__device__ __forceinline__ float bf2f(short s) {
  unsigned int u = ((unsigned int)(unsigned short)s) << 16;
  float f;
  __builtin_memcpy(&f, &u, 4);
  return f;
}
__device__ __forceinline__ short f2bf(float f) {
  unsigned int u;
  __builtin_memcpy(&u, &f, 4);
  u += 0x7fffu + ((u >> 16) & 1u);  // round-to-nearest-even
  return (short)(u >> 16);
}
__device__ __forceinline__ bf16x8 as_bf(int4 v) {
  union { int4 i; bf16x8 b; } u; u.i = v; return u.b;
}

// Agent-scope relaxed (sc1: bypass per-XCD L2, coherent at LLC) state access.
__device__ __forceinline__ float ldf(const float* p) {
  return __hip_atomic_load((float*)p, __ATOMIC_RELAXED, __HIP_MEMORY_SCOPE_AGENT);
}
__device__ __forceinline__ void stf(float* p, float v) {
  __hip_atomic_store(p, v, __ATOMIC_RELAXED, __HIP_MEMORY_SCOPE_AGENT);
}
// 16B of bf16 state as 4 coherent dword loads
__device__ __forceinline__ int4 ld_sc16(const short* p) {
  unsigned* w = (unsigned*)p;
  int4 v;
  v.x = (int)__hip_atomic_load(w + 0, __ATOMIC_RELAXED, __HIP_MEMORY_SCOPE_AGENT);
  v.y = (int)__hip_atomic_load(w + 1, __ATOMIC_RELAXED, __HIP_MEMORY_SCOPE_AGENT);
  v.z = (int)__hip_atomic_load(w + 2, __ATOMIC_RELAXED, __HIP_MEMORY_SCOPE_AGENT);
  v.w = (int)__hip_atomic_load(w + 3, __ATOMIC_RELAXED, __HIP_MEMORY_SCOPE_AGENT);
  return v;
}

// Grid barrier with ZERO cache maintenance:
//  - RELAXED fetch_add (plain global_atomic_add; a RELEASE here emits
//    buffer_wbl2 = full per-XCD L2 writeback walk on gfx95x — that was the
//    constant ~32us/phase in rounds 5-6: ~25 serialized walks per XCD).
//  - Explicit s_waitcnt(0) by EVERY thread first: each wave drains its own
//    sc1 stores to the LLC before anyone signals arrival (no reliance on
//    compiler-inserted waits, no fence instructions).
//  - RELAXED spin (no buffer_inv); state moves via sc1 ops, not caches.
__device__ __forceinline__ void grid_barrier(unsigned int* bar, unsigned int target) {
  __builtin_amdgcn_s_waitcnt(0);
  __syncthreads();
  if (threadIdx.x == 0) {
    __hip_atomic_fetch_add(bar, 1u, __ATOMIC_RELAXED, __HIP_MEMORY_SCOPE_AGENT);
    while (__hip_atomic_load(bar, __ATOMIC_RELAXED, __HIP_MEMORY_SCOPE_AGENT) < target)
      __builtin_amdgcn_s_sleep(16);
  }
  __syncthreads();
  asm volatile("" ::: "memory");
}

// Per-wave GEMM, 16x32 output tile, K=1024, no LDS/no __syncthreads.
// A (state): coherent dword loads from LLC. B (weights): plain cached loads,
// permanently L2-hot (never invalidated). 8-deep register pipeline.
__device__ __forceinline__ void wave_gemm16(
    const short* __restrict__ A, int mb, int lm, int q,
    const short* __restrict__ Bw, int bstride, int nb,
    f32x4 (&acc)[2]) {
  const short* ap  = A  + (size_t)(mb + lm) * Hh + q * 8;
  const short* bp0 = Bw + (size_t)(nb + lm) * bstride + q * 8;
  const short* bp1 = bp0 + (size_t)16 * bstride;
  int4 av[8], b0v[8], b1v[8];
#pragma unroll
  for (int c = 0; c < 8; ++c) {
    av[c]  = ld_sc16(ap + c * 32);
    b0v[c] = *(const int4*)(bp0 + c * 32);
    b1v[c] = *(const int4*)(bp1 + c * 32);
  }
#pragma unroll
  for (int c = 0; c < 32; ++c) {
    const int s = c & 7;
    const bf16x8 a  = as_bf(av[s]);
    const bf16x8 b0 = as_bf(b0v[s]);
    const bf16x8 b1 = as_bf(b1v[s]);
    if (c + 8 < 32) {
      av[s]  = ld_sc16(ap + (c + 8) * 32);
      b0v[s] = *(const int4*)(bp0 + (c + 8) * 32);
      b1v[s] = *(const int4*)(bp1 + (c + 8) * 32);
    }
    acc[0] = __builtin_amdgcn_mfma_f32_16x16x32_bf16(a, b0, acc[0], 0, 0, 0);
    acc[1] = __builtin_amdgcn_mfma_f32_16x16x32_bf16(a, b1, acc[1], 0, 0, 0);
  }
}

// C/D layout (verified m89/m91): col = lane&15, row = (lane>>4)*4 + reg
#define TL(MB, NB, ...) do {                                               \
    _Pragma("unroll")                                                      \
    for (int n = 0; n < 2; ++n) {                                          \
      _Pragma("unroll")                                                    \
      for (int r = 0; r < 4; ++r) {                                        \
        const int row = (MB) + q * 4 + r;                                  \
        const int col = (NB) + n * 16 + lm;                                \
        const float z = acc[n][r];                                         \
        __VA_ARGS__;                                                       \
      } } } while (0)

// pack bf16 pair across lane (lm, lm^1) and store one coherent dword from even lm
#define ST_BF16_PAIR(BASE, ROW, COL, HV) do {                              \
    const int _ov = __shfl_xor((int)(unsigned short)(HV), 1, 64);          \
    if ((lm & 1) == 0) {                                                   \
      const unsigned _pk = (unsigned)(unsigned short)(HV) | ((unsigned)_ov << 16); \
      __hip_atomic_store((unsigned*)((BASE) + (ROW) * Hh + (COL)), _pk,    \
                         __ATOMIC_RELAXED, __HIP_MEMORY_SCOPE_AGENT);      \
    } } while (0)

#define ZACC() do { const f32x4 z4 = {0.f,0.f,0.f,0.f}; acc[0] = z4; acc[1] = z4; } while (0)

struct RP {
  short* h1a; short* h1b; short* h2bf;
  float* h2f; float* uf; float* ug1f; float* acc2f; float* o1f;
  const short* prex;
  const short* whh1; const short* wih2; const short* whh2;
  const short* wg; const short* wo1; const short* wo2;
  const float* b_ih2; const float* b_hh2;
  const float* bg; const float* bo1; const float* bo2;
  float* out;
  unsigned int* bar;
};

// Wave tasks (gw = blockIdx*4 + wave, 0..783):
//  Phase A: [0,256) h1 | [256,512) acc2 | [512,768) u-gate | [768,784) out(t-1)
//  Phase B: [0,256) h2 blend | [256,512) ug1 | [512,528) o1 head | rest idle
__global__ void __launch_bounds__(256, 1) rnn_kernel(RP p) {
  const int tid = threadIdx.x;
  const int lane = tid & 63;
  const int wv = tid >> 6;
  const int lm = lane & 15;
  const int q = lane >> 4;
  const int gw = blockIdx.x * 4 + wv;

  int roleA, gA;
  if      (gw < 256) { roleA = 0; gA = gw; }
  else if (gw < 512) { roleA = 1; gA = gw - 256; }
  else if (gw < 768) { roleA = 2; gA = gw - 512; }
  else               { roleA = 3; gA = gw - 768; }
  const int mbA = (roleA == 3) ? (gA >> 1) * 16 : (gA >> 5) * 16;
  const int nbA = (roleA == 3) ? (gA & 1) * 32  : (gA & 31) * 32;
  const short* WA; int bsA;
  switch (roleA) {
    case 0: WA = p.whh1;    bsA = Hh;     break;
    case 1: WA = p.whh2;    bsA = Hh;     break;
    case 2: WA = p.wg + Hh; bsA = 2 * Hh; break;   // Wg, h2 half
    default: WA = p.wo2;    bsA = Hh;     break;
  }
  float bA0 = 0.f, bA1 = 0.f;
  {
    const int c0 = nbA + lm, c1 = nbA + 16 + lm;
    if (roleA == 1) { bA0 = p.b_ih2[c0] + p.b_hh2[c0]; bA1 = p.b_ih2[c1] + p.b_hh2[c1]; }
    else if (roleA == 2) { bA0 = p.bg[c0];  bA1 = p.bg[c1]; }
    else if (roleA == 3) { bA0 = p.bo2[c0]; bA1 = p.bo2[c1]; }
  }

  int roleB, gB;
  if      (gw < 256) { roleB = 4; gB = gw; }
  else if (gw < 512) { roleB = 5; gB = gw - 256; }
  else if (gw < 528) { roleB = 6; gB = gw - 512; }
  else               { roleB = 7; gB = 0; }       // idle
  const int mbB = (roleB == 6) ? (gB >> 1) * 16 : (gB >> 5) * 16;
  const int nbB = (roleB == 6) ? (gB & 1) * 32  : (gB & 31) * 32;
  const short* WB = p.wo1; int bsB = Hh;
  if (roleB == 4) { WB = p.wih2; bsB = Hh; }
  else if (roleB == 5) { WB = p.wg; bsB = 2 * Hh; }  // Wg, h1 half
  float bB0 = 0.f, bB1 = 0.f;
  if (roleB == 6) { bB0 = p.bo1[nbB + lm]; bB1 = p.bo1[nbB + 16 + lm]; }

  f32x4 acc[2];
  unsigned int gen = 0;
  for (int t = 0; t < Tt; ++t) {
    const short* h1in  = (t & 1) ? p.h1b : p.h1a;
    short*       h1out = (t & 1) ? p.h1a : p.h1b;
    // ---------------- Phase A ----------------
    if (roleA == 0) {
      // prefetch prex (plain cached; streamed once) before the GEMM
      short prs[2][4];
      const short* pr = p.prex + (size_t)t * Bb * Hh;
#pragma unroll
      for (int n = 0; n < 2; ++n)
#pragma unroll
        for (int r = 0; r < 4; ++r)
          prs[n][r] = pr[(size_t)(mbA + q * 4 + r) * Hh + nbA + n * 16 + lm];
      ZACC();
      wave_gemm16(h1in, mbA, lm, q, WA, bsA, nbA, acc);
      TL(mbA, nbA, {
        const short hv = f2bf(tanhf(z + bf2f(prs[n][r])));
        ST_BF16_PAIR(h1out, row, col, hv);
      });
    } else if (roleA == 1) {
      ZACC();
      wave_gemm16(p.h2bf, mbA, lm, q, WA, bsA, nbA, acc);
      TL(mbA, nbA, { stf(p.acc2f + row * Hh + col, z + (n ? bA1 : bA0)); });
    } else if (roleA == 2) {
      if (t > 0) {
        float ex[2][4];
#pragma unroll
        for (int n = 0; n < 2; ++n)
#pragma unroll
          for (int r = 0; r < 4; ++r)
            ex[n][r] = ldf(p.ug1f + (mbA + q * 4 + r) * Hh + nbA + n * 16 + lm);
        ZACC();
        wave_gemm16(p.h2bf, mbA, lm, q, WA, bsA, nbA, acc);
        TL(mbA, nbA, {
          const float s = z + ex[n][r] + (n ? bA1 : bA0);
          stf(p.uf + row * Hh + col, 1.0f / (1.0f + expf(-s)));
        });
      }
    } else {
      if (t > 0) {
        float ex[2][4];
#pragma unroll
        for (int n = 0; n < 2; ++n)
#pragma unroll
          for (int r = 0; r < 4; ++r)
            ex[n][r] = ldf(p.o1f + (mbA + q * 4 + r) * Oo + nbA + n * 16 + lm);
        ZACC();
        wave_gemm16(p.h2bf, mbA, lm, q, WA, bsA, nbA, acc);
        TL(mbA, nbA, {
          p.out[(size_t)row * (Tt * Oo) + (size_t)(t - 1) * Oo + col] =
              ex[n][r] + tanhf(z + (n ? bA1 : bA0));
        });
      }
    }
    gen += NBLK;
    grid_barrier(p.bar, gen);
    // ---------------- Phase B ----------------
    if (roleB == 4) {
      float a2[2][4], uu[2][4], h2o[2][4];
#pragma unroll
      for (int n = 0; n < 2; ++n)
#pragma unroll
        for (int r = 0; r < 4; ++r) {
          const int idx = (mbB + q * 4 + r) * Hh + nbB + n * 16 + lm;
          a2[n][r]  = ldf(p.acc2f + idx);
          uu[n][r]  = ldf(p.uf + idx);
          h2o[n][r] = p.h2f[idx];        // XCD-local (same wave wrote it)
        }
      ZACC();
      wave_gemm16(h1out, mbB, lm, q, WB, bsB, nbB, acc);
      TL(mbB, nbB, {
        const int idx = row * Hh + col;
        const float hn = tanhf(z + a2[n][r]);
        const float nv = fmaf(uu[n][r], hn - h2o[n][r], h2o[n][r]);
        p.h2f[idx] = nv;
        const short hv = f2bf(nv);
        ST_BF16_PAIR(p.h2bf, row, col, hv);
      });
    } else if (roleB == 5) {
      ZACC();
      wave_gemm16(h1out, mbB, lm, q, WB, bsB, nbB, acc);
      TL(mbB, nbB, { stf(p.ug1f + row * Hh + col, z); });
    } else if (roleB == 6) {
      ZACC();
      wave_gemm16(h1out, mbB, lm, q, WB, bsB, nbB, acc);
      TL(mbB, nbB, { stf(p.o1f + row * Oo + col, tanhf(z + (n ? bB1 : bB0))); });
    }
    gen += NBLK;
    grid_barrier(p.bar, gen);
  }
  // tail: out rows for t = Tt-1 (state visible via coherent loads)
  if (roleA == 3) {
    float ex[2][4];
#pragma unroll
    for (int n = 0; n < 2; ++n)
#pragma unroll
      for (int r = 0; r < 4; ++r)
        ex[n][r] = ldf(p.o1f + (mbA + q * 4 + r) * Oo + nbA + n * 16 + lm);
    ZACC();
    wave_gemm16(p.h2bf, mbA, lm, q, WA, bsA, nbA, acc);
    TL(mbA, nbA, {
      p.out[(size_t)row * (Tt * Oo) + (size_t)(Tt - 1) * Oo + col] =
          ex[n][r] + tanhf(z + (n ? bA1 : bA0));
    });
  }
}

// pre_x[t][b][j] = x[b,t,:] @ W_ih1[j,:] + b_ih1[j] + b_hh1[j]  (stored bf16)
__global__ void __launch_bounds__(256) prex_kernel(
    const float* __restrict__ x, const float* __restrict__ wih1,
    const float* __restrict__ b_ih1, const float* __restrict__ b_hh1,
    short* __restrict__ prex) {
  const int tid = threadIdx.x;
  const int lane = tid & 63;
  const int wv = tid >> 6;
  const int lm = lane & 15;
  const int q = lane >> 4;
  const int bm = blockIdx.x >> 4;
  const int bn = blockIdx.x & 15;
  const int rowbase = bm * 64;
  const int col = bn * 64 + wv * 16 + lm;

  const f32x4 z4 = {0.f, 0.f, 0.f, 0.f};
  f32x4 acc[4];
#pragma unroll
  for (int mt = 0; mt < 4; ++mt) acc[mt] = z4;

#pragma unroll
  for (int kc = 0; kc < 2; ++kc) {
    const float* bp = wih1 + col * 64 + kc * 32 + q * 8;
    bf16x8 bf;
#pragma unroll
    for (int j = 0; j < 8; ++j) bf[j] = f2bf(bp[j]);
#pragma unroll
    for (int mt = 0; mt < 4; ++mt) {
      const float* ap = x + (size_t)(rowbase + mt * 16 + lm) * 64 + kc * 32 + q * 8;
      bf16x8 af;
#pragma unroll
      for (int j = 0; j < 8; ++j) af[j] = f2bf(ap[j]);
      acc[mt] = __builtin_amdgcn_mfma_f32_16x16x32_bf16(af, bf, acc[mt], 0, 0, 0);
    }
  }
  const float bia = b_ih1[col] + b_hh1[col];
#pragma unroll
  for (int mt = 0; mt < 4; ++mt) {
#pragma unroll
    for (int r = 0; r < 4; ++r) {
      const int row = rowbase + mt * 16 + q * 4 + r;  // row = b*256 + t
      const int b  = row >> 8;
      const int tt = row & 255;
      prex[((size_t)tt * Bb + b) * Hh + col] = f2bf(acc[mt][r] + bia);
    }
  }
}

__global__ void conv_kernel(const float* __restrict__ s, short* __restrict__ d, int n) {
  int i = blockIdx.x * blockDim.x + threadIdx.x;
  const int stride = gridDim.x * blockDim.x;
  for (; i < n; i += stride) d[i] = f2bf(s[i]);
}

__global__ void init_kernel(short* h1a, short* h1b, short* h2bf, float* h2f,
                            float* uf, unsigned int* bar) {
  const int i = blockIdx.x * blockDim.x + threadIdx.x;  // exactly 128*1024
  h1a[i] = 0; h1b[i] = 0; h2bf[i] = 0; h2f[i] = 0.f; uf[i] = 1.0f;
  if (i == 0) *bar = 0u;
}

extern "C" void kernel_launch(void* const* d_in, const int* in_sizes, int n_in,
                              void* d_out, int out_size, void* d_ws, size_t ws_size,
                              hipStream_t stream) {
  (void)in_sizes; (void)n_in; (void)out_size; (void)ws_size;
  const float* x      = (const float*)d_in[0];
  const float* W_ih1  = (const float*)d_in[1];
  const float* b_ih1  = (const float*)d_in[2];
  const float* W_hh1  = (const float*)d_in[3];
  const float* b_hh1  = (const float*)d_in[4];
  const float* W_ih2  = (const float*)d_in[5];
  const float* b_ih2  = (const float*)d_in[6];
  const float* W_hh2  = (const float*)d_in[7];
  const float* b_hh2  = (const float*)d_in[8];
  const float* Wg     = (const float*)d_in[9];
  const float* bg     = (const float*)d_in[10];
  const float* Wo1    = (const float*)d_in[11];
  const float* bo1    = (const float*)d_in[12];
  const float* Wo2    = (const float*)d_in[13];
  const float* bo2    = (const float*)d_in[14];

  char* ws = (char*)d_ws;
  size_t off = 0;
  auto alloc = [&](size_t bytes) -> void* {
    void* ptr = ws + off;
    off += (bytes + 255) & ~(size_t)255;
    return ptr;
  };
  short* whh1 = (short*)alloc((size_t)Hh * Hh * 2);
  short* wih2 = (short*)alloc((size_t)Hh * Hh * 2);
  short* whh2 = (short*)alloc((size_t)Hh * Hh * 2);
  short* wg   = (short*)alloc((size_t)Hh * 2 * Hh * 2);
  short* wo1  = (short*)alloc((size_t)Oo * Hh * 2);
  short* wo2  = (short*)alloc((size_t)Oo * Hh * 2);
  short* prex = (short*)alloc((size_t)Bb * Tt * Hh * 2);
  short* h1a  = (short*)alloc((size_t)Bb * Hh * 2);
  short* h1b  = (short*)alloc((size_t)Bb * Hh * 2);
  short* h2bf = (short*)alloc((size_t)Bb * Hh * 2);
  float* h2f  = (float*)alloc((size_t)Bb * Hh * 4);
  float* uf   = (float*)alloc((size_t)Bb * Hh * 4);
  float* ug1f = (float*)alloc((size_t)Bb * Hh * 4);
  float* acc2f= (float*)alloc((size_t)Bb * Hh * 4);
  float* o1f  = (float*)alloc((size_t)Bb * Oo * 4);
  unsigned int* bar = (unsigned int*)alloc(256);

  conv_kernel<<<1024, 256, 0, stream>>>(W_hh1, whh1, Hh * Hh);
  conv_kernel<<<1024, 256, 0, stream>>>(W_ih2, wih2, Hh * Hh);
  conv_kernel<<<1024, 256, 0, stream>>>(W_hh2, whh2, Hh * Hh);
  conv_kernel<<<2048, 256, 0, stream>>>(Wg,    wg,   Hh * 2 * Hh);
  conv_kernel<<<256,  256, 0, stream>>>(Wo1,   wo1,  Oo * Hh);
  conv_kernel<<<256,  256, 0, stream>>>(Wo2,   wo2,  Oo * Hh);
  init_kernel<<<512, 256, 0, stream>>>(h1a, h1b, h2bf, h2f, uf, bar);
  prex_kernel<<<8192, 256, 0, stream>>>(x, W_ih1, b_ih1, b_hh1, prex);

  RP p;
  p.h1a = h1a; p.h1b = h1b; p.h2bf = h2bf;
  p.h2f = h2f; p.uf = uf; p.ug1f = ug1f; p.acc2f = acc2f; p.o1f = o1f;
  p.prex = prex;
  p.whh1 = whh1; p.wih2 = wih2; p.whh2 = whh2;
  p.wg = wg; p.wo1 = wo1; p.wo2 = wo2;
  p.b_ih2 = b_ih2; p.b_hh2 = b_hh2;
  p.bg = bg; p.bo1 = bo1; p.bo2 = bo2;
  p.out = (float*)d_out;
  p.bar = bar;

  rnn_kernel<<<NBLK, 256, 0, stream>>>(p);
}

// Round 8
// 8871.965 us; speedup vs baseline: 5.8137x; 1.6162x over previous
//
#include <hip/hip_runtime.h>
#include <cstddef>

using bf16x8 = __attribute__((ext_vector_type(8))) short;
using f32x4  = __attribute__((ext_vector_type(4))) float;

constexpr int Bb = 128;
constexpr int Tt = 256;
constexpr int Hh = 1024;
constexpr int Oo = 64;
constexpr int NBLK = 196;
constexpr int FLAG_STRIDE = 32;   // dwords -> 128B between flags (separate lines)

__device__ __forceinline__ float bf2f(short s) {
  unsigned int u = ((unsigned int)(unsigned short)s) << 16;
  float f;
  __builtin_memcpy(&f, &u, 4);
  return f;
}
__device__ __forceinline__ short f2bf(float f) {
  unsigned int u;
  __builtin_memcpy(&u, &f, 4);
  u += 0x7fffu + ((u >> 16) & 1u);  // round-to-nearest-even
  return (short)(u >> 16);
}
__device__ __forceinline__ bf16x8 as_bf(int4 v) {
  union { int4 i; bf16x8 b; } u; u.i = v; return u.b;
}

// Agent-scope relaxed (sc1: bypass per-XCD L2, coherent at LLC) state access.
__device__ __forceinline__ float ldf(const float* p) {
  return __hip_atomic_load((float*)p, __ATOMIC_RELAXED, __HIP_MEMORY_SCOPE_AGENT);
}
__device__ __forceinline__ void stf(float* p, float v) {
  __hip_atomic_store(p, v, __ATOMIC_RELAXED, __HIP_MEMORY_SCOPE_AGENT);
}
__device__ __forceinline__ unsigned ldu(const unsigned* p) {
  return __hip_atomic_load((unsigned*)p, __ATOMIC_RELAXED, __HIP_MEMORY_SCOPE_AGENT);
}
// 16B of bf16 state as 2 coherent 64-bit loads
__device__ __forceinline__ int4 ld_sc16(const short* p) {
  const unsigned long long* w = (const unsigned long long*)p;
  unsigned long long lo = __hip_atomic_load((unsigned long long*)(w + 0), __ATOMIC_RELAXED, __HIP_MEMORY_SCOPE_AGENT);
  unsigned long long hi = __hip_atomic_load((unsigned long long*)(w + 1), __ATOMIC_RELAXED, __HIP_MEMORY_SCOPE_AGENT);
  int4 v;
  v.x = (int)(lo & 0xffffffffu); v.y = (int)(lo >> 32);
  v.z = (int)(hi & 0xffffffffu); v.w = (int)(hi >> 32);
  return v;
}

// RMW-free grid barrier.
// Rounds 5-7 all pinned at ~28us/phase with 196 same-line atomic fetch-adds:
// same-address RMWs serialize at one LLC slice (~140ns each, ~27us total).
// Here: arrival = relaxed store to the block's OWN flag (parallel, no RMW);
// completion = wave-0 polls all 256 padded flags with 4 vector loads/lane
// (distinct lines -> pipelined, ~1 LLC round trip per poll).
// gen is monotonic; flags[i>=NBLK] preset to 0xFFFFFFFF (always pass).
__device__ __forceinline__ void grid_barrier(unsigned* flags, unsigned gen,
                                             int bid, int tid) {
  __builtin_amdgcn_s_waitcnt(0);   // drain this wave's sc1 state stores to LLC
  __syncthreads();
  if (tid == 0)
    __hip_atomic_store(flags + (size_t)bid * FLAG_STRIDE, gen,
                       __ATOMIC_RELAXED, __HIP_MEMORY_SCOPE_AGENT);
  if (tid < 64) {
    const unsigned* f = flags + (size_t)tid * FLAG_STRIDE;
    for (;;) {
      const unsigned a = ldu(f);
      const unsigned b = ldu(f +  64 * FLAG_STRIDE);
      const unsigned c = ldu(f + 128 * FLAG_STRIDE);
      const unsigned d = ldu(f + 192 * FLAG_STRIDE);
      if (__all((a >= gen) && (b >= gen) && (c >= gen) && (d >= gen))) break;
      __builtin_amdgcn_s_sleep(2);
    }
  }
  __syncthreads();
  asm volatile("" ::: "memory");
}

// Per-wave GEMM, 16x32 output tile, K=1024, no LDS/no __syncthreads.
// A (state): coherent 64-bit loads from LLC. B (weights): plain cached loads.
// 8-deep register pipeline.
__device__ __forceinline__ void wave_gemm16(
    const short* __restrict__ A, int mb, int lm, int q,
    const short* __restrict__ Bw, int bstride, int nb,
    f32x4 (&acc)[2]) {
  const short* ap  = A  + (size_t)(mb + lm) * Hh + q * 8;
  const short* bp0 = Bw + (size_t)(nb + lm) * bstride + q * 8;
  const short* bp1 = bp0 + (size_t)16 * bstride;
  int4 av[8], b0v[8], b1v[8];
#pragma unroll
  for (int c = 0; c < 8; ++c) {
    av[c]  = ld_sc16(ap + c * 32);
    b0v[c] = *(const int4*)(bp0 + c * 32);
    b1v[c] = *(const int4*)(bp1 + c * 32);
  }
#pragma unroll
  for (int c = 0; c < 32; ++c) {
    const int s = c & 7;
    const bf16x8 a  = as_bf(av[s]);
    const bf16x8 b0 = as_bf(b0v[s]);
    const bf16x8 b1 = as_bf(b1v[s]);
    if (c + 8 < 32) {
      av[s]  = ld_sc16(ap + (c + 8) * 32);
      b0v[s] = *(const int4*)(bp0 + (c + 8) * 32);
      b1v[s] = *(const int4*)(bp1 + (c + 8) * 32);
    }
    acc[0] = __builtin_amdgcn_mfma_f32_16x16x32_bf16(a, b0, acc[0], 0, 0, 0);
    acc[1] = __builtin_amdgcn_mfma_f32_16x16x32_bf16(a, b1, acc[1], 0, 0, 0);
  }
}

// C/D layout (verified m89/m91): col = lane&15, row = (lane>>4)*4 + reg
#define TL(MB, NB, ...) do {                                               \
    _Pragma("unroll")                                                      \
    for (int n = 0; n < 2; ++n) {                                          \
      _Pragma("unroll")                                                    \
      for (int r = 0; r < 4; ++r) {                                        \
        const int row = (MB) + q * 4 + r;                                  \
        const int col = (NB) + n * 16 + lm;                                \
        const float z = acc[n][r];                                         \
        __VA_ARGS__;                                                       \
      } } } while (0)

// pack bf16 pair across lane (lm, lm^1) and store one coherent dword from even lm
#define ST_BF16_PAIR(BASE, ROW, COL, HV) do {                              \
    const int _ov = __shfl_xor((int)(unsigned short)(HV), 1, 64);          \
    if ((lm & 1) == 0) {                                                   \
      const unsigned _pk = (unsigned)(unsigned short)(HV) | ((unsigned)_ov << 16); \
      __hip_atomic_store((unsigned*)((BASE) + (ROW) * Hh + (COL)), _pk,    \
                         __ATOMIC_RELAXED, __HIP_MEMORY_SCOPE_AGENT);      \
    } } while (0)

#define ZACC() do { const f32x4 z4 = {0.f,0.f,0.f,0.f}; acc[0] = z4; acc[1] = z4; } while (0)

struct RP {
  short* h1a; short* h1b; short* h2bf;
  float* h2f; float* uf; float* ug1f; float* acc2f; float* o1f;
  const short* prex;
  const short* whh1; const short* wih2; const short* whh2;
  const short* wg; const short* wo1; const short* wo2;
  const float* b_ih2; const float* b_hh2;
  const float* bg; const float* bo1; const float* bo2;
  float* out;
  unsigned* flags;
};

// Wave tasks (gw = blockIdx*4 + wave, 0..783):
//  Phase A: [0,256) h1 | [256,512) acc2 | [512,768) u-gate | [768,784) out(t-1)
//  Phase B: [0,256) h2 blend | [256,512) ug1 | [512,528) o1 head | rest idle
__global__ void __launch_bounds__(256, 1) rnn_kernel(RP p) {
  const int tid = threadIdx.x;
  const int lane = tid & 63;
  const int wv = tid >> 6;
  const int lm = lane & 15;
  const int q = lane >> 4;
  const int bid = blockIdx.x;
  const int gw = bid * 4 + wv;

  int roleA, gA;
  if      (gw < 256) { roleA = 0; gA = gw; }
  else if (gw < 512) { roleA = 1; gA = gw - 256; }
  else if (gw < 768) { roleA = 2; gA = gw - 512; }
  else               { roleA = 3; gA = gw - 768; }
  const int mbA = (roleA == 3) ? (gA >> 1) * 16 : (gA >> 5) * 16;
  const int nbA = (roleA == 3) ? (gA & 1) * 32  : (gA & 31) * 32;
  const short* WA; int bsA;
  switch (roleA) {
    case 0: WA = p.whh1;    bsA = Hh;     break;
    case 1: WA = p.whh2;    bsA = Hh;     break;
    case 2: WA = p.wg + Hh; bsA = 2 * Hh; break;   // Wg, h2 half
    default: WA = p.wo2;    bsA = Hh;     break;
  }
  float bA0 = 0.f, bA1 = 0.f;
  {
    const int c0 = nbA + lm, c1 = nbA + 16 + lm;
    if (roleA == 1) { bA0 = p.b_ih2[c0] + p.b_hh2[c0]; bA1 = p.b_ih2[c1] + p.b_hh2[c1]; }
    else if (roleA == 2) { bA0 = p.bg[c0];  bA1 = p.bg[c1]; }
    else if (roleA == 3) { bA0 = p.bo2[c0]; bA1 = p.bo2[c1]; }
  }

  int roleB, gB;
  if      (gw < 256) { roleB = 4; gB = gw; }
  else if (gw < 512) { roleB = 5; gB = gw - 256; }
  else if (gw < 528) { roleB = 6; gB = gw - 512; }
  else               { roleB = 7; gB = 0; }       // idle
  const int mbB = (roleB == 6) ? (gB >> 1) * 16 : (gB >> 5) * 16;
  const int nbB = (roleB == 6) ? (gB & 1) * 32  : (gB & 31) * 32;
  const short* WB = p.wo1; int bsB = Hh;
  if (roleB == 4) { WB = p.wih2; bsB = Hh; }
  else if (roleB == 5) { WB = p.wg; bsB = 2 * Hh; }  // Wg, h1 half
  float bB0 = 0.f, bB1 = 0.f;
  if (roleB == 6) { bB0 = p.bo1[nbB + lm]; bB1 = p.bo1[nbB + 16 + lm]; }

  f32x4 acc[2];
  unsigned gen = 0;
  for (int t = 0; t < Tt; ++t) {
    const short* h1in  = (t & 1) ? p.h1b : p.h1a;
    short*       h1out = (t & 1) ? p.h1a : p.h1b;
    // ---------------- Phase A ----------------
    if (roleA == 0) {
      // prefetch prex (plain cached; streamed once) before the GEMM
      short prs[2][4];
      const short* pr = p.prex + (size_t)t * Bb * Hh;
#pragma unroll
      for (int n = 0; n < 2; ++n)
#pragma unroll
        for (int r = 0; r < 4; ++r)
          prs[n][r] = pr[(size_t)(mbA + q * 4 + r) * Hh + nbA + n * 16 + lm];
      ZACC();
      wave_gemm16(h1in, mbA, lm, q, WA, bsA, nbA, acc);
      TL(mbA, nbA, {
        const short hv = f2bf(tanhf(z + bf2f(prs[n][r])));
        ST_BF16_PAIR(h1out, row, col, hv);
      });
    } else if (roleA == 1) {
      ZACC();
      wave_gemm16(p.h2bf, mbA, lm, q, WA, bsA, nbA, acc);
      TL(mbA, nbA, { stf(p.acc2f + row * Hh + col, z + (n ? bA1 : bA0)); });
    } else if (roleA == 2) {
      if (t > 0) {
        float ex[2][4];
#pragma unroll
        for (int n = 0; n < 2; ++n)
#pragma unroll
          for (int r = 0; r < 4; ++r)
            ex[n][r] = ldf(p.ug1f + (mbA + q * 4 + r) * Hh + nbA + n * 16 + lm);
        ZACC();
        wave_gemm16(p.h2bf, mbA, lm, q, WA, bsA, nbA, acc);
        TL(mbA, nbA, {
          const float s = z + ex[n][r] + (n ? bA1 : bA0);
          stf(p.uf + row * Hh + col, 1.0f / (1.0f + expf(-s)));
        });
      }
    } else {
      if (t > 0) {
        float ex[2][4];
#pragma unroll
        for (int n = 0; n < 2; ++n)
#pragma unroll
          for (int r = 0; r < 4; ++r)
            ex[n][r] = ldf(p.o1f + (mbA + q * 4 + r) * Oo + nbA + n * 16 + lm);
        ZACC();
        wave_gemm16(p.h2bf, mbA, lm, q, WA, bsA, nbA, acc);
        TL(mbA, nbA, {
          p.out[(size_t)row * (Tt * Oo) + (size_t)(t - 1) * Oo + col] =
              ex[n][r] + tanhf(z + (n ? bA1 : bA0));
        });
      }
    }
    ++gen;
    grid_barrier(p.flags, gen, bid, tid);
    // ---------------- Phase B ----------------
    if (roleB == 4) {
      float a2[2][4], uu[2][4], h2o[2][4];
#pragma unroll
      for (int n = 0; n < 2; ++n)
#pragma unroll
        for (int r = 0; r < 4; ++r) {
          const int idx = (mbB + q * 4 + r) * Hh + nbB + n * 16 + lm;
          a2[n][r]  = ldf(p.acc2f + idx);
          uu[n][r]  = ldf(p.uf + idx);
          h2o[n][r] = p.h2f[idx];        // XCD-local (same wave wrote it)
        }
      ZACC();
      wave_gemm16(h1out, mbB, lm, q, WB, bsB, nbB, acc);
      TL(mbB, nbB, {
        const int idx = row * Hh + col;
        const float hn = tanhf(z + a2[n][r]);
        const float nv = fmaf(uu[n][r], hn - h2o[n][r], h2o[n][r]);
        p.h2f[idx] = nv;
        const short hv = f2bf(nv);
        ST_BF16_PAIR(p.h2bf, row, col, hv);
      });
    } else if (roleB == 5) {
      ZACC();
      wave_gemm16(h1out, mbB, lm, q, WB, bsB, nbB, acc);
      TL(mbB, nbB, { stf(p.ug1f + row * Hh + col, z); });
    } else if (roleB == 6) {
      ZACC();
      wave_gemm16(h1out, mbB, lm, q, WB, bsB, nbB, acc);
      TL(mbB, nbB, { stf(p.o1f + row * Oo + col, tanhf(z + (n ? bB1 : bB0))); });
    }
    ++gen;
    grid_barrier(p.flags, gen, bid, tid);
  }
  // tail: out rows for t = Tt-1 (state visible via coherent loads)
  if (roleA == 3) {
    float ex[2][4];
#pragma unroll
    for (int n = 0; n < 2; ++n)
#pragma unroll
      for (int r = 0; r < 4; ++r)
        ex[n][r] = ldf(p.o1f + (mbA + q * 4 + r) * Oo + nbA + n * 16 + lm);
    ZACC();
    wave_gemm16(p.h2bf, mbA, lm, q, WA, bsA, nbA, acc);
    TL(mbA, nbA, {
      p.out[(size_t)row * (Tt * Oo) + (size_t)(Tt - 1) * Oo + col] =
          ex[n][r] + tanhf(z + (n ? bA1 : bA0));
    });
  }
}

// pre_x[t][b][j] = x[b,t,:] @ W_ih1[j,:] + b_ih1[j] + b_hh1[j]  (stored bf16)
__global__ void __launch_bounds__(256) prex_kernel(
    const float* __restrict__ x, const float* __restrict__ wih1,
    const float* __restrict__ b_ih1, const float* __restrict__ b_hh1,
    short* __restrict__ prex) {
  const int tid = threadIdx.x;
  const int lane = tid & 63;
  const int wv = tid >> 6;
  const int lm = lane & 15;
  const int q = lane >> 4;
  const int bm = blockIdx.x >> 4;
  const int bn = blockIdx.x & 15;
  const int rowbase = bm * 64;
  const int col = bn * 64 + wv * 16 + lm;

  const f32x4 z4 = {0.f, 0.f, 0.f, 0.f};
  f32x4 acc[4];
#pragma unroll
  for (int mt = 0; mt < 4; ++mt) acc[mt] = z4;

#pragma unroll
  for (int kc = 0; kc < 2; ++kc) {
    const float* bp = wih1 + col * 64 + kc * 32 + q * 8;
    bf16x8 bf;
#pragma unroll
    for (int j = 0; j < 8; ++j) bf[j] = f2bf(bp[j]);
#pragma unroll
    for (int mt = 0; mt < 4; ++mt) {
      const float* ap = x + (size_t)(rowbase + mt * 16 + lm) * 64 + kc * 32 + q * 8;
      bf16x8 af;
#pragma unroll
      for (int j = 0; j < 8; ++j) af[j] = f2bf(ap[j]);
      acc[mt] = __builtin_amdgcn_mfma_f32_16x16x32_bf16(af, bf, acc[mt], 0, 0, 0);
    }
  }
  const float bia = b_ih1[col] + b_hh1[col];
#pragma unroll
  for (int mt = 0; mt < 4; ++mt) {
#pragma unroll
    for (int r = 0; r < 4; ++r) {
      const int row = rowbase + mt * 16 + q * 4 + r;  // row = b*256 + t
      const int b  = row >> 8;
      const int tt = row & 255;
      prex[((size_t)tt * Bb + b) * Hh + col] = f2bf(acc[mt][r] + bia);
    }
  }
}

__global__ void conv_kernel(const float* __restrict__ s, short* __restrict__ d, int n) {
  int i = blockIdx.x * blockDim.x + threadIdx.x;
  const int stride = gridDim.x * blockDim.x;
  for (; i < n; i += stride) d[i] = f2bf(s[i]);
}

__global__ void init_kernel(short* h1a, short* h1b, short* h2bf, float* h2f,
                            float* uf, unsigned* flags) {
  const int i = blockIdx.x * blockDim.x + threadIdx.x;  // exactly 128*1024
  h1a[i] = 0; h1b[i] = 0; h2bf[i] = 0; h2f[i] = 0.f; uf[i] = 1.0f;
  if (i < 256) flags[i * FLAG_STRIDE] = (i < NBLK) ? 0u : 0xFFFFFFFFu;
}

extern "C" void kernel_launch(void* const* d_in, const int* in_sizes, int n_in,
                              void* d_out, int out_size, void* d_ws, size_t ws_size,
                              hipStream_t stream) {
  (void)in_sizes; (void)n_in; (void)out_size; (void)ws_size;
  const float* x      = (const float*)d_in[0];
  const float* W_ih1  = (const float*)d_in[1];
  const float* b_ih1  = (const float*)d_in[2];
  const float* W_hh1  = (const float*)d_in[3];
  const float* b_hh1  = (const float*)d_in[4];
  const float* W_ih2  = (const float*)d_in[5];
  const float* b_ih2  = (const float*)d_in[6];
  const float* W_hh2  = (const float*)d_in[7];
  const float* b_hh2  = (const float*)d_in[8];
  const float* Wg     = (const float*)d_in[9];
  const float* bg     = (const float*)d_in[10];
  const float* Wo1    = (const float*)d_in[11];
  const float* bo1    = (const float*)d_in[12];
  const float* Wo2    = (const float*)d_in[13];
  const float* bo2    = (const float*)d_in[14];

  char* ws = (char*)d_ws;
  size_t off = 0;
  auto alloc = [&](size_t bytes) -> void* {
    void* ptr = ws + off;
    off += (bytes + 255) & ~(size_t)255;
    return ptr;
  };
  short* whh1 = (short*)alloc((size_t)Hh * Hh * 2);
  short* wih2 = (short*)alloc((size_t)Hh * Hh * 2);
  short* whh2 = (short*)alloc((size_t)Hh * Hh * 2);
  short* wg   = (short*)alloc((size_t)Hh * 2 * Hh * 2);
  short* wo1  = (short*)alloc((size_t)Oo * Hh * 2);
  short* wo2  = (short*)alloc((size_t)Oo * Hh * 2);
  short* prex = (short*)alloc((size_t)Bb * Tt * Hh * 2);
  short* h1a  = (short*)alloc((size_t)Bb * Hh * 2);
  short* h1b  = (short*)alloc((size_t)Bb * Hh * 2);
  short* h2bf = (short*)alloc((size_t)Bb * Hh * 2);
  float* h2f  = (float*)alloc((size_t)Bb * Hh * 4);
  float* uf   = (float*)alloc((size_t)Bb * Hh * 4);
  float* ug1f = (float*)alloc((size_t)Bb * Hh * 4);
  float* acc2f= (float*)alloc((size_t)Bb * Hh * 4);
  float* o1f  = (float*)alloc((size_t)Bb * Oo * 4);
  unsigned* flags = (unsigned*)alloc(256 * FLAG_STRIDE * 4);   // 32 KB

  conv_kernel<<<1024, 256, 0, stream>>>(W_hh1, whh1, Hh * Hh);
  conv_kernel<<<1024, 256, 0, stream>>>(W_ih2, wih2, Hh * Hh);
  conv_kernel<<<1024, 256, 0, stream>>>(W_hh2, whh2, Hh * Hh);
  conv_kernel<<<2048, 256, 0, stream>>>(Wg,    wg,   Hh * 2 * Hh);
  conv_kernel<<<256,  256, 0, stream>>>(Wo1,   wo1,  Oo * Hh);
  conv_kernel<<<256,  256, 0, stream>>>(Wo2,   wo2,  Oo * Hh);
  init_kernel<<<512, 256, 0, stream>>>(h1a, h1b, h2bf, h2f, uf, flags);
  prex_kernel<<<8192, 256, 0, stream>>>(x, W_ih1, b_ih1, b_hh1, prex);

  RP p;
  p.h1a = h1a; p.h1b = h1b; p.h2bf = h2bf;
  p.h2f = h2f; p.uf = uf; p.ug1f = ug1f; p.acc2f = acc2f; p.o1f = o1f;
  p.prex = prex;
  p.whh1 = whh1; p.wih2 = wih2; p.whh2 = whh2;
  p.wg = wg; p.wo1 = wo1; p.wo2 = wo2;
  p.b_ih2 = b_ih2; p.b_hh2 = b_hh2;
  p.bg = bg; p.bo1 = bo1; p.bo2 = bo2;
  p.out = (float*)d_out;
  p.flags = flags;

  rnn_kernel<<<NBLK, 256, 0, stream>>>(p);
}

// Round 9
// 8770.149 us; speedup vs baseline: 5.8812x; 1.0116x over previous
//
#include <hip/hip_runtime.h>
#include <cstddef>

using bf16x8 = __attribute__((ext_vector_type(8))) short;
using f32x4  = __attribute__((ext_vector_type(4))) float;

constexpr int Bb = 128;
constexpr int Tt = 256;
constexpr int Hh = 1024;
constexpr int Oo = 64;
constexpr int NBLK = 196;
constexpr int FLAG_STRIDE = 32;   // dwords -> 128B between flags (separate lines)

__device__ __forceinline__ float bf2f(short s) {
  unsigned int u = ((unsigned int)(unsigned short)s) << 16;
  float f;
  __builtin_memcpy(&f, &u, 4);
  return f;
}
__device__ __forceinline__ short f2bf(float f) {
  unsigned int u;
  __builtin_memcpy(&u, &f, 4);
  u += 0x7fffu + ((u >> 16) & 1u);  // round-to-nearest-even
  return (short)(u >> 16);
}
__device__ __forceinline__ bf16x8 as_bf(int4 v) {
  union { int4 i; bf16x8 b; } u; u.i = v; return u.b;
}

// Agent-scope relaxed (sc1: bypass per-XCD L2, coherent at LLC) state access.
__device__ __forceinline__ float ldf(const float* p) {
  return __hip_atomic_load((float*)p, __ATOMIC_RELAXED, __HIP_MEMORY_SCOPE_AGENT);
}
__device__ __forceinline__ void stf(float* p, float v) {
  __hip_atomic_store(p, v, __ATOMIC_RELAXED, __HIP_MEMORY_SCOPE_AGENT);
}
__device__ __forceinline__ unsigned ldu(const unsigned* p) {
  return __hip_atomic_load((unsigned*)p, __ATOMIC_RELAXED, __HIP_MEMORY_SCOPE_AGENT);
}
// 16B of bf16 state as 2 coherent 64-bit loads
__device__ __forceinline__ int4 ld_sc16(const short* p) {
  const unsigned long long* w = (const unsigned long long*)p;
  unsigned long long lo = __hip_atomic_load((unsigned long long*)(w + 0), __ATOMIC_RELAXED, __HIP_MEMORY_SCOPE_AGENT);
  unsigned long long hi = __hip_atomic_load((unsigned long long*)(w + 1), __ATOMIC_RELAXED, __HIP_MEMORY_SCOPE_AGENT);
  int4 v;
  v.x = (int)(lo & 0xffffffffu); v.y = (int)(lo >> 32);
  v.z = (int)(hi & 0xffffffffu); v.w = (int)(hi >> 32);
  return v;
}

// Hierarchical RMW-free grid barrier.
// Round-8's all-poll-all design was an LLC DDoS: 196 waves x 256 distinct
// lines x ~3 rounds/us = ~7x the useful work traffic. Here:
//  - arrival: each block stores its OWN flag line (parallel, no RMW);
//  - block 0 wave-0 is the only aggregator: polls the 256 padded flags
//    (4 loads/lane), then publishes a single go word;
//  - all other blocks poll ONLY the go line (64 lanes, same address ->
//    one coalesced line request per wave per round). ~100x less traffic.
// gen is monotonic; flags[i>=NBLK] preset to 0xFFFFFFFF (always pass).
__device__ __forceinline__ void grid_barrier(unsigned* flags, unsigned* go,
                                             unsigned gen, int bid, int tid) {
  __builtin_amdgcn_s_waitcnt(0);   // drain this wave's sc1 state stores to LLC
  __syncthreads();
  if (tid == 0)
    __hip_atomic_store(flags + (size_t)bid * FLAG_STRIDE, gen,
                       __ATOMIC_RELAXED, __HIP_MEMORY_SCOPE_AGENT);
  if (bid == 0) {
    if (tid < 64) {
      const unsigned* f = flags + (size_t)tid * FLAG_STRIDE;
      for (;;) {
        const unsigned a = ldu(f);
        const unsigned b = ldu(f +  64 * FLAG_STRIDE);
        const unsigned c = ldu(f + 128 * FLAG_STRIDE);
        const unsigned d = ldu(f + 192 * FLAG_STRIDE);
        if (__all((a >= gen) && (b >= gen) && (c >= gen) && (d >= gen))) break;
        __builtin_amdgcn_s_sleep(2);
      }
      if (tid == 0)
        __hip_atomic_store(go, gen, __ATOMIC_RELAXED, __HIP_MEMORY_SCOPE_AGENT);
    }
  } else if (tid < 64) {
    while (ldu(go) < gen)
      __builtin_amdgcn_s_sleep(2);
  }
  __syncthreads();
  asm volatile("" ::: "memory");
}

// Per-wave GEMM, 16x32 output tile, K=1024, no LDS/no __syncthreads.
// A (state): coherent 64-bit loads from LLC. B (weights): plain cached loads.
// 8-deep register pipeline.
__device__ __forceinline__ void wave_gemm16(
    const short* __restrict__ A, int mb, int lm, int q,
    const short* __restrict__ Bw, int bstride, int nb,
    f32x4 (&acc)[2]) {
  const short* ap  = A  + (size_t)(mb + lm) * Hh + q * 8;
  const short* bp0 = Bw + (size_t)(nb + lm) * bstride + q * 8;
  const short* bp1 = bp0 + (size_t)16 * bstride;
  int4 av[8], b0v[8], b1v[8];
#pragma unroll
  for (int c = 0; c < 8; ++c) {
    av[c]  = ld_sc16(ap + c * 32);
    b0v[c] = *(const int4*)(bp0 + c * 32);
    b1v[c] = *(const int4*)(bp1 + c * 32);
  }
#pragma unroll
  for (int c = 0; c < 32; ++c) {
    const int s = c & 7;
    const bf16x8 a  = as_bf(av[s]);
    const bf16x8 b0 = as_bf(b0v[s]);
    const bf16x8 b1 = as_bf(b1v[s]);
    if (c + 8 < 32) {
      av[s]  = ld_sc16(ap + (c + 8) * 32);
      b0v[s] = *(const int4*)(bp0 + (c + 8) * 32);
      b1v[s] = *(const int4*)(bp1 + (c + 8) * 32);
    }
    acc[0] = __builtin_amdgcn_mfma_f32_16x16x32_bf16(a, b0, acc[0], 0, 0, 0);
    acc[1] = __builtin_amdgcn_mfma_f32_16x16x32_bf16(a, b1, acc[1], 0, 0, 0);
  }
}

// C/D layout (verified m89/m91): col = lane&15, row = (lane>>4)*4 + reg
#define TL(MB, NB, ...) do {                                               \
    _Pragma("unroll")                                                      \
    for (int n = 0; n < 2; ++n) {                                          \
      _Pragma("unroll")                                                    \
      for (int r = 0; r < 4; ++r) {                                        \
        const int row = (MB) + q * 4 + r;                                  \
        const int col = (NB) + n * 16 + lm;                                \
        const float z = acc[n][r];                                         \
        __VA_ARGS__;                                                       \
      } } } while (0)

// pack bf16 pair across lane (lm, lm^1) and store one coherent dword from even lm
#define ST_BF16_PAIR(BASE, ROW, COL, HV) do {                              \
    const int _ov = __shfl_xor((int)(unsigned short)(HV), 1, 64);          \
    if ((lm & 1) == 0) {                                                   \
      const unsigned _pk = (unsigned)(unsigned short)(HV) | ((unsigned)_ov << 16); \
      __hip_atomic_store((unsigned*)((BASE) + (ROW) * Hh + (COL)), _pk,    \
                         __ATOMIC_RELAXED, __HIP_MEMORY_SCOPE_AGENT);      \
    } } while (0)

#define ZACC() do { const f32x4 z4 = {0.f,0.f,0.f,0.f}; acc[0] = z4; acc[1] = z4; } while (0)

struct RP {
  short* h1a; short* h1b; short* h2bf;
  float* h2f; float* uf; float* ug1f; float* acc2f; float* o1f;
  const short* prex;
  const short* whh1; const short* wih2; const short* whh2;
  const short* wg; const short* wo1; const short* wo2;
  const float* b_ih2; const float* b_hh2;
  const float* bg; const float* bo1; const float* bo2;
  float* out;
  unsigned* flags;
  unsigned* go;
};

// Wave tasks (gw = blockIdx*4 + wave, 0..783):
//  Phase A: [0,256) h1 | [256,512) acc2 | [512,768) u-gate | [768,784) out(t-1)
//  Phase B: [0,256) h2 blend | [256,512) ug1 | [512,528) o1 head | rest idle
__global__ void __launch_bounds__(256, 1) rnn_kernel(RP p) {
  const int tid = threadIdx.x;
  const int lane = tid & 63;
  const int wv = tid >> 6;
  const int lm = lane & 15;
  const int q = lane >> 4;
  const int bid = blockIdx.x;
  const int gw = bid * 4 + wv;

  int roleA, gA;
  if      (gw < 256) { roleA = 0; gA = gw; }
  else if (gw < 512) { roleA = 1; gA = gw - 256; }
  else if (gw < 768) { roleA = 2; gA = gw - 512; }
  else               { roleA = 3; gA = gw - 768; }
  const int mbA = (roleA == 3) ? (gA >> 1) * 16 : (gA >> 5) * 16;
  const int nbA = (roleA == 3) ? (gA & 1) * 32  : (gA & 31) * 32;
  const short* WA; int bsA;
  switch (roleA) {
    case 0: WA = p.whh1;    bsA = Hh;     break;
    case 1: WA = p.whh2;    bsA = Hh;     break;
    case 2: WA = p.wg + Hh; bsA = 2 * Hh; break;   // Wg, h2 half
    default: WA = p.wo2;    bsA = Hh;     break;
  }
  float bA0 = 0.f, bA1 = 0.f;
  {
    const int c0 = nbA + lm, c1 = nbA + 16 + lm;
    if (roleA == 1) { bA0 = p.b_ih2[c0] + p.b_hh2[c0]; bA1 = p.b_ih2[c1] + p.b_hh2[c1]; }
    else if (roleA == 2) { bA0 = p.bg[c0];  bA1 = p.bg[c1]; }
    else if (roleA == 3) { bA0 = p.bo2[c0]; bA1 = p.bo2[c1]; }
  }

  int roleB, gB;
  if      (gw < 256) { roleB = 4; gB = gw; }
  else if (gw < 512) { roleB = 5; gB = gw - 256; }
  else if (gw < 528) { roleB = 6; gB = gw - 512; }
  else               { roleB = 7; gB = 0; }       // idle
  const int mbB = (roleB == 6) ? (gB >> 1) * 16 : (gB >> 5) * 16;
  const int nbB = (roleB == 6) ? (gB & 1) * 32  : (gB & 31) * 32;
  const short* WB = p.wo1; int bsB = Hh;
  if (roleB == 4) { WB = p.wih2; bsB = Hh; }
  else if (roleB == 5) { WB = p.wg; bsB = 2 * Hh; }  // Wg, h1 half
  float bB0 = 0.f, bB1 = 0.f;
  if (roleB == 6) { bB0 = p.bo1[nbB + lm]; bB1 = p.bo1[nbB + 16 + lm]; }

  f32x4 acc[2];
  unsigned gen = 0;
  for (int t = 0; t < Tt; ++t) {
    const short* h1in  = (t & 1) ? p.h1b : p.h1a;
    short*       h1out = (t & 1) ? p.h1a : p.h1b;
    // ---------------- Phase A ----------------
    if (roleA == 0) {
      // prefetch prex (plain cached; streamed once) before the GEMM
      short prs[2][4];
      const short* pr = p.prex + (size_t)t * Bb * Hh;
#pragma unroll
      for (int n = 0; n < 2; ++n)
#pragma unroll
        for (int r = 0; r < 4; ++r)
          prs[n][r] = pr[(size_t)(mbA + q * 4 + r) * Hh + nbA + n * 16 + lm];
      ZACC();
      wave_gemm16(h1in, mbA, lm, q, WA, bsA, nbA, acc);
      TL(mbA, nbA, {
        const short hv = f2bf(tanhf(z + bf2f(prs[n][r])));
        ST_BF16_PAIR(h1out, row, col, hv);
      });
    } else if (roleA == 1) {
      ZACC();
      wave_gemm16(p.h2bf, mbA, lm, q, WA, bsA, nbA, acc);
      TL(mbA, nbA, { stf(p.acc2f + row * Hh + col, z + (n ? bA1 : bA0)); });
    } else if (roleA == 2) {
      if (t > 0) {
        float ex[2][4];
#pragma unroll
        for (int n = 0; n < 2; ++n)
#pragma unroll
          for (int r = 0; r < 4; ++r)
            ex[n][r] = ldf(p.ug1f + (mbA + q * 4 + r) * Hh + nbA + n * 16 + lm);
        ZACC();
        wave_gemm16(p.h2bf, mbA, lm, q, WA, bsA, nbA, acc);
        TL(mbA, nbA, {
          const float s = z + ex[n][r] + (n ? bA1 : bA0);
          stf(p.uf + row * Hh + col, 1.0f / (1.0f + expf(-s)));
        });
      }
    } else {
      if (t > 0) {
        float ex[2][4];
#pragma unroll
        for (int n = 0; n < 2; ++n)
#pragma unroll
          for (int r = 0; r < 4; ++r)
            ex[n][r] = ldf(p.o1f + (mbA + q * 4 + r) * Oo + nbA + n * 16 + lm);
        ZACC();
        wave_gemm16(p.h2bf, mbA, lm, q, WA, bsA, nbA, acc);
        TL(mbA, nbA, {
          p.out[(size_t)row * (Tt * Oo) + (size_t)(t - 1) * Oo + col] =
              ex[n][r] + tanhf(z + (n ? bA1 : bA0));
        });
      }
    }
    ++gen;
    grid_barrier(p.flags, p.go, gen, bid, tid);
    // ---------------- Phase B ----------------
    if (roleB == 4) {
      float a2[2][4], uu[2][4], h2o[2][4];
#pragma unroll
      for (int n = 0; n < 2; ++n)
#pragma unroll
        for (int r = 0; r < 4; ++r) {
          const int idx = (mbB + q * 4 + r) * Hh + nbB + n * 16 + lm;
          a2[n][r]  = ldf(p.acc2f + idx);
          uu[n][r]  = ldf(p.uf + idx);
          h2o[n][r] = p.h2f[idx];        // XCD-local (same wave wrote it)
        }
      ZACC();
      wave_gemm16(h1out, mbB, lm, q, WB, bsB, nbB, acc);
      TL(mbB, nbB, {
        const int idx = row * Hh + col;
        const float hn = tanhf(z + a2[n][r]);
        const float nv = fmaf(uu[n][r], hn - h2o[n][r], h2o[n][r]);
        p.h2f[idx] = nv;
        const short hv = f2bf(nv);
        ST_BF16_PAIR(p.h2bf, row, col, hv);
      });
    } else if (roleB == 5) {
      ZACC();
      wave_gemm16(h1out, mbB, lm, q, WB, bsB, nbB, acc);
      TL(mbB, nbB, { stf(p.ug1f + row * Hh + col, z); });
    } else if (roleB == 6) {
      ZACC();
      wave_gemm16(h1out, mbB, lm, q, WB, bsB, nbB, acc);
      TL(mbB, nbB, { stf(p.o1f + row * Oo + col, tanhf(z + (n ? bB1 : bB0))); });
    }
    ++gen;
    grid_barrier(p.flags, p.go, gen, bid, tid);
  }
  // tail: out rows for t = Tt-1 (state visible via coherent loads)
  if (roleA == 3) {
    float ex[2][4];
#pragma unroll
    for (int n = 0; n < 2; ++n)
#pragma unroll
      for (int r = 0; r < 4; ++r)
        ex[n][r] = ldf(p.o1f + (mbA + q * 4 + r) * Oo + nbA + n * 16 + lm);
    ZACC();
    wave_gemm16(p.h2bf, mbA, lm, q, WA, bsA, nbA, acc);
    TL(mbA, nbA, {
      p.out[(size_t)row * (Tt * Oo) + (size_t)(Tt - 1) * Oo + col] =
          ex[n][r] + tanhf(z + (n ? bA1 : bA0));
    });
  }
}

// pre_x[t][b][j] = x[b,t,:] @ W_ih1[j,:] + b_ih1[j] + b_hh1[j]  (stored bf16)
__global__ void __launch_bounds__(256) prex_kernel(
    const float* __restrict__ x, const float* __restrict__ wih1,
    const float* __restrict__ b_ih1, const float* __restrict__ b_hh1,
    short* __restrict__ prex) {
  const int tid = threadIdx.x;
  const int lane = tid & 63;
  const int wv = tid >> 6;
  const int lm = lane & 15;
  const int q = lane >> 4;
  const int bm = blockIdx.x >> 4;
  const int bn = blockIdx.x & 15;
  const int rowbase = bm * 64;
  const int col = bn * 64 + wv * 16 + lm;

  const f32x4 z4 = {0.f, 0.f, 0.f, 0.f};
  f32x4 acc[4];
#pragma unroll
  for (int mt = 0; mt < 4; ++mt) acc[mt] = z4;

#pragma unroll
  for (int kc = 0; kc < 2; ++kc) {
    const float* bp = wih1 + col * 64 + kc * 32 + q * 8;
    bf16x8 bf;
#pragma unroll
    for (int j = 0; j < 8; ++j) bf[j] = f2bf(bp[j]);
#pragma unroll
    for (int mt = 0; mt < 4; ++mt) {
      const float* ap = x + (size_t)(rowbase + mt * 16 + lm) * 64 + kc * 32 + q * 8;
      bf16x8 af;
#pragma unroll
      for (int j = 0; j < 8; ++j) af[j] = f2bf(ap[j]);
      acc[mt] = __builtin_amdgcn_mfma_f32_16x16x32_bf16(af, bf, acc[mt], 0, 0, 0);
    }
  }
  const float bia = b_ih1[col] + b_hh1[col];
#pragma unroll
  for (int mt = 0; mt < 4; ++mt) {
#pragma unroll
    for (int r = 0; r < 4; ++r) {
      const int row = rowbase + mt * 16 + q * 4 + r;  // row = b*256 + t
      const int b  = row >> 8;
      const int tt = row & 255;
      prex[((size_t)tt * Bb + b) * Hh + col] = f2bf(acc[mt][r] + bia);
    }
  }
}

__global__ void conv_kernel(const float* __restrict__ s, short* __restrict__ d, int n) {
  int i = blockIdx.x * blockDim.x + threadIdx.x;
  const int stride = gridDim.x * blockDim.x;
  for (; i < n; i += stride) d[i] = f2bf(s[i]);
}

__global__ void init_kernel(short* h1a, short* h1b, short* h2bf, float* h2f,
                            float* uf, unsigned* flags, unsigned* go) {
  const int i = blockIdx.x * blockDim.x + threadIdx.x;  // exactly 128*1024
  h1a[i] = 0; h1b[i] = 0; h2bf[i] = 0; h2f[i] = 0.f; uf[i] = 1.0f;
  if (i < 256) flags[i * FLAG_STRIDE] = (i < NBLK) ? 0u : 0xFFFFFFFFu;
  if (i == 0) *go = 0u;
}

extern "C" void kernel_launch(void* const* d_in, const int* in_sizes, int n_in,
                              void* d_out, int out_size, void* d_ws, size_t ws_size,
                              hipStream_t stream) {
  (void)in_sizes; (void)n_in; (void)out_size; (void)ws_size;
  const float* x      = (const float*)d_in[0];
  const float* W_ih1  = (const float*)d_in[1];
  const float* b_ih1  = (const float*)d_in[2];
  const float* W_hh1  = (const float*)d_in[3];
  const float* b_hh1  = (const float*)d_in[4];
  const float* W_ih2  = (const float*)d_in[5];
  const float* b_ih2  = (const float*)d_in[6];
  const float* W_hh2  = (const float*)d_in[7];
  const float* b_hh2  = (const float*)d_in[8];
  const float* Wg     = (const float*)d_in[9];
  const float* bg     = (const float*)d_in[10];
  const float* Wo1    = (const float*)d_in[11];
  const float* bo1    = (const float*)d_in[12];
  const float* Wo2    = (const float*)d_in[13];
  const float* bo2    = (const float*)d_in[14];

  char* ws = (char*)d_ws;
  size_t off = 0;
  auto alloc = [&](size_t bytes) -> void* {
    void* ptr = ws + off;
    off += (bytes + 255) & ~(size_t)255;
    return ptr;
  };
  short* whh1 = (short*)alloc((size_t)Hh * Hh * 2);
  short* wih2 = (short*)alloc((size_t)Hh * Hh * 2);
  short* whh2 = (short*)alloc((size_t)Hh * Hh * 2);
  short* wg   = (short*)alloc((size_t)Hh * 2 * Hh * 2);
  short* wo1  = (short*)alloc((size_t)Oo * Hh * 2);
  short* wo2  = (short*)alloc((size_t)Oo * Hh * 2);
  short* prex = (short*)alloc((size_t)Bb * Tt * Hh * 2);
  short* h1a  = (short*)alloc((size_t)Bb * Hh * 2);
  short* h1b  = (short*)alloc((size_t)Bb * Hh * 2);
  short* h2bf = (short*)alloc((size_t)Bb * Hh * 2);
  float* h2f  = (float*)alloc((size_t)Bb * Hh * 4);
  float* uf   = (float*)alloc((size_t)Bb * Hh * 4);
  float* ug1f = (float*)alloc((size_t)Bb * Hh * 4);
  float* acc2f= (float*)alloc((size_t)Bb * Hh * 4);
  float* o1f  = (float*)alloc((size_t)Bb * Oo * 4);
  unsigned* flags = (unsigned*)alloc(256 * FLAG_STRIDE * 4);   // 32 KB
  unsigned* go    = (unsigned*)alloc(256);

  conv_kernel<<<1024, 256, 0, stream>>>(W_hh1, whh1, Hh * Hh);
  conv_kernel<<<1024, 256, 0, stream>>>(W_ih2, wih2, Hh * Hh);
  conv_kernel<<<1024, 256, 0, stream>>>(W_hh2, whh2, Hh * Hh);
  conv_kernel<<<2048, 256, 0, stream>>>(Wg,    wg,   Hh * 2 * Hh);
  conv_kernel<<<256,  256, 0, stream>>>(Wo1,   wo1,  Oo * Hh);
  conv_kernel<<<256,  256, 0, stream>>>(Wo2,   wo2,  Oo * Hh);
  init_kernel<<<512, 256, 0, stream>>>(h1a, h1b, h2bf, h2f, uf, flags, go);
  prex_kernel<<<8192, 256, 0, stream>>>(x, W_ih1, b_ih1, b_hh1, prex);

  RP p;
  p.h1a = h1a; p.h1b = h1b; p.h2bf = h2bf;
  p.h2f = h2f; p.uf = uf; p.ug1f = ug1f; p.acc2f = acc2f; p.o1f = o1f;
  p.prex = prex;
  p.whh1 = whh1; p.wih2 = wih2; p.whh2 = whh2;
  p.wg = wg; p.wo1 = wo1; p.wo2 = wo2;
  p.b_ih2 = b_ih2; p.b_hh2 = b_hh2;
  p.bg = bg; p.bo1 = bo1; p.bo2 = bo2;
  p.out = (float*)d_out;
  p.flags = flags;
  p.go = go;

  rnn_kernel<<<NBLK, 256, 0, stream>>>(p);
}